// Round 5
// baseline (479.465 us; speedup 1.0000x reference)
//
#include <hip/hip_runtime.h>
#include <hip/hip_bf16.h>

#define NN 65536
#define NE 524288
#define DF 128
#define NG 512
#define NCLS 10

typedef __bf16 bf16x8 __attribute__((ext_vector_type(8)));
typedef float f32x4 __attribute__((ext_vector_type(4)));
typedef ushort u16x8 __attribute__((ext_vector_type(8)));

__device__ __forceinline__ float bl(uint x) { return __uint_as_float(x << 16); }
__device__ __forceinline__ float bh(uint x) { return __uint_as_float(x & 0xffff0000u); }
__device__ __forceinline__ ushort f2b(float f) {
    uint u = __float_as_uint(f);
    return (ushort)((u + 0x7fffu + ((u >> 16) & 1u)) >> 16);  // RN-even
}

// ---------------- degree histograms (fire-and-forget atomics) ----------------
__global__ void k_degrees(const int* __restrict__ src, const int* __restrict__ dst,
                          int* __restrict__ deg_out, int* __restrict__ deg_in) {
    int e = blockIdx.x * blockDim.x + threadIdx.x;
    if (e < NE) {
        atomicAdd(&deg_out[src[e]], 1);
        atomicAdd(&deg_in[dst[e]], 1);
    }
}

__global__ void k_norms(const int* __restrict__ deg_out, const int* __restrict__ deg_in,
                        float* __restrict__ ns, float* __restrict__ nd) {
    int v = blockIdx.x * blockDim.x + threadIdx.x;
    if (v < NN) {
        ns[v] = rsqrtf((float)max(deg_out[v], 1));
        nd[v] = rsqrtf((float)max(deg_in[v], 1));
    }
}

// exclusive scan of deg_in (NN ints) -> rp[0..NN]
__global__ void k_scan(const int* __restrict__ deg, int* __restrict__ rp) {
    __shared__ int tmp[1024];
    int t = threadIdx.x;
    int base = t * 64;
    int s = 0;
    for (int i = 0; i < 64; i++) s += deg[base + i];
    tmp[t] = s;
    __syncthreads();
    for (int off = 1; off < 1024; off <<= 1) {
        int v = (t >= off) ? tmp[t - off] : 0;
        __syncthreads();
        tmp[t] += v;
        __syncthreads();
    }
    int run = tmp[t] - s;
    for (int i = 0; i < 64; i++) {
        int d = deg[base + i];
        rp[base + i] = run;
        run += d;
    }
    if (t == 1023) rp[NN] = run;
}

__global__ void k_scatter(const int* __restrict__ src, const int* __restrict__ dst,
                          const int* __restrict__ rp, int* __restrict__ cursor,
                          int* __restrict__ col) {
    int e = blockIdx.x * blockDim.x + threadIdx.x;
    if (e < NE) {
        int d = dst[e];
        int p = atomicAdd(&cursor[d], 1);
        col[rp[d] + p] = src[e];
    }
}

// xs(bf16) = hx * norm_src; one dword (2 elems) per thread
__global__ void k_scale(const float* __restrict__ hx, const float* __restrict__ ns,
                        uint* __restrict__ xs) {
    int i = blockIdx.x * blockDim.x + threadIdx.x;  // over NN*64 dwords
    float2 v = ((const float2*)hx)[i];
    float s = ns[i >> 6];
    xs[i] = (uint)f2b(v.x * s) | ((uint)f2b(v.y * s) << 16);
}

// W (fp32 [k][n]) -> Wt (bf16 [n][k])
__global__ void k_wconv(const float* __restrict__ W, ushort* __restrict__ Wt) {
    int t = blockIdx.x * blockDim.x + threadIdx.x;  // 16384
    int n = t >> 7, k = t & 127;
    Wt[n * 128 + k] = f2b(W[k * 128 + n]);
}

// ---------------------------------------------------------------------------
// Fused: out = relu( (norm_dst * gather-sum(xs)) @ W + b ) * (scale? ns : 1)
// TWO waves per block, 16 node rows, grid = NN/16 = 4096 blocks of 128.
//   - edge-split gather: wave w owns edge idx (i-s)%2==w
//   - unroll-4: 16 uint4 in flight = ONE latency exposure for mean degree 8
//     (VGPR cap 128 via launch_bounds(128,4); R1's spill was the (64,4) cap)
//   - FULL cross-wave exchange (16 KB LDS), then BOTH waves do MFMA:
//     wave w computes n-columns [w*64, w*64+64) and stores its half-rows
// Lane (l&15)=row, (l>>4)=k-quad.
// ---------------------------------------------------------------------------
#define UNP(k, v) { a[k][0] += bl(v.x); a[k][1] += bh(v.x); \
                    a[k][2] += bl(v.y); a[k][3] += bh(v.y); \
                    a[k][4] += bl(v.z); a[k][5] += bh(v.z); \
                    a[k][6] += bl(v.w); a[k][7] += bh(v.w); }

__global__ __launch_bounds__(128, 4) void k_fused(
        const uint4* __restrict__ X,      // xs as uint4 rows: node*16 chunks
        const int* __restrict__ rp, const int* __restrict__ col,
        const float* __restrict__ nd, const float* __restrict__ ns,
        const uint4* __restrict__ Wg,     // Wt bf16 [n][k] as uint4: n*16+chunk
        const float* __restrict__ b, int do_scale,
        ushort* __restrict__ out) {
    // As[w]: [grp 0..7][lane 0..63] f32x4, 16B stride (2 lanes/bank: free)
    __shared__ f32x4 As[2][8 * 64];       // 16 KB
    int t = threadIdx.x;
    int wv = t >> 6, lane = t & 63;
    int r = lane & 15;      // row within tile
    int q = lane >> 4;      // k-quad (gather) / row-quad (C)
    int nb = blockIdx.x * 16;             // first node of this block
    int node = nb + r;

    int s = rp[node], e = rp[node + 1];
    float a[4][8] = {};
    int i = s + wv;                       // stride-2 ownership
    for (; i + 6 < e; i += 8) {           // 4 owned edges, 16 loads in flight
        size_t b0 = (size_t)col[i] * 16 + q;
        size_t b1 = (size_t)col[i + 2] * 16 + q;
        size_t b2 = (size_t)col[i + 4] * 16 + q;
        size_t b3 = (size_t)col[i + 6] * 16 + q;
        uint4 x0 = X[b0], x1 = X[b0 + 4], x2 = X[b0 + 8], x3 = X[b0 + 12];
        uint4 y0 = X[b1], y1 = X[b1 + 4], y2 = X[b1 + 8], y3 = X[b1 + 12];
        uint4 z0 = X[b2], z1 = X[b2 + 4], z2 = X[b2 + 8], z3 = X[b2 + 12];
        uint4 u0 = X[b3], u1 = X[b3 + 4], u2 = X[b3 + 8], u3 = X[b3 + 12];
        UNP(0, x0) UNP(1, x1) UNP(2, x2) UNP(3, x3)
        UNP(0, y0) UNP(1, y1) UNP(2, y2) UNP(3, y3)
        UNP(0, z0) UNP(1, z1) UNP(2, z2) UNP(3, z3)
        UNP(0, u0) UNP(1, u1) UNP(2, u2) UNP(3, u3)
    }
    for (; i + 2 < e; i += 4) {           // 2 owned edges
        size_t b0 = (size_t)col[i] * 16 + q;
        size_t b1 = (size_t)col[i + 2] * 16 + q;
        uint4 x0 = X[b0],      y0 = X[b1];
        uint4 x1 = X[b0 + 4],  y1 = X[b1 + 4];
        uint4 x2 = X[b0 + 8],  y2 = X[b1 + 8];
        uint4 x3 = X[b0 + 12], y3 = X[b1 + 12];
        UNP(0, x0) UNP(1, x1) UNP(2, x2) UNP(3, x3)
        UNP(0, y0) UNP(1, y1) UNP(2, y2) UNP(3, y3)
    }
    if (i < e) {
        size_t b0 = (size_t)col[i] * 16 + q;
        uint4 x0 = X[b0], x1 = X[b0 + 4], x2 = X[b0 + 8], x3 = X[b0 + 12];
        UNP(0, x0) UNP(1, x1) UNP(2, x2) UNP(3, x3)
    }

    // full cross-wave exchange: each wave publishes partials, reads the other's
    #pragma unroll
    for (int g = 0; g < 8; g++) {
        f32x4 v = { a[g >> 1][(g & 1) * 4 + 0], a[g >> 1][(g & 1) * 4 + 1],
                    a[g >> 1][(g & 1) * 4 + 2], a[g >> 1][(g & 1) * 4 + 3] };
        As[wv][g * 64 + lane] = v;
    }
    __syncthreads();
    #pragma unroll
    for (int g = 0; g < 8; g++) {
        f32x4 v = As[wv ^ 1][g * 64 + lane];
        a[g >> 1][(g & 1) * 4 + 0] += v[0];
        a[g >> 1][(g & 1) * 4 + 1] += v[1];
        a[g >> 1][(g & 1) * 4 + 2] += v[2];
        a[g >> 1][(g & 1) * 4 + 3] += v[3];
    }
    __syncthreads();   // As reads done before epilogue reuses the LDS

    // convert to bf16 A-fragments (scale by norm_dst)
    float sc = nd[node];
    bf16x8 afr[4];
    #pragma unroll
    for (int ks = 0; ks < 4; ks++) {
        union { u16x8 u; bf16x8 f; } cv;
        #pragma unroll
        for (int j = 0; j < 8; j++) cv.u[j] = f2b(a[ks][j] * sc);
        afr[ks] = cv.f;
    }

    // MFMA: wave w computes C[16][w*64 .. w*64+64)
    f32x4 cacc[4] = {};
    #pragma unroll
    for (int ks = 0; ks < 4; ks++) {
        #pragma unroll
        for (int nj = 0; nj < 4; nj++) {
            int ni = wv * 4 + nj;
            union { uint4 u; bf16x8 f; } bw;
            bw.u = Wg[(size_t)(ni * 16 + r) * 16 + ks * 4 + q];
            cacc[nj] = __builtin_amdgcn_mfma_f32_16x16x32_bf16(
                afr[ks], bw.f, cacc[nj], 0, 0, 0);
        }
    }

    // epilogue: bias + relu + (ns fold) -> bf16 into LDS (reuse As), then
    // each wave stores its own half-rows (128B segments, coalesced)
    ushort* Cs = (ushort*)As;             // [16][128]
    float sc4[4];
    #pragma unroll
    for (int rg = 0; rg < 4; rg++)
        sc4[rg] = do_scale ? ns[nb + q * 4 + rg] : 1.f;
    #pragma unroll
    for (int nj = 0; nj < 4; nj++) {
        int c = (wv * 4 + nj) * 16 + r;
        float bb = b[c];
        #pragma unroll
        for (int rg = 0; rg < 4; rg++) {
            float v = fmaxf(cacc[nj][rg] + bb, 0.f) * sc4[rg];
            Cs[(q * 4 + rg) * 128 + c] = f2b(v);
        }
    }
    // wave w wrote cols [w*64, w*64+64) of all 16 rows; store that half
    const uint4* Cs4 = (const uint4*)Cs;  // [16][16] uint4
    #pragma unroll
    for (int it = 0; it < 2; it++) {
        int linear = it * 64 + lane;      // 0..127
        int row = linear >> 3, cj = linear & 7;
        uint4* Og = (uint4*)(out + (size_t)(nb + row) * 128);
        Og[wv * 8 + cj] = Cs4[row * 16 + wv * 8 + cj];
    }
}

// graph row pointers via binary search on sorted graph_id
__global__ void k_gptr(const int* __restrict__ gid, int* __restrict__ gptr) {
    int g = blockIdx.x * blockDim.x + threadIdx.x;
    if (g <= NG) {
        int lo = 0, hi = NN;
        while (lo < hi) {
            int mid = (lo + hi) >> 1;
            if (gid[mid] < g) lo = mid + 1; else hi = mid;
        }
        gptr[g] = lo;
    }
}

// mean-pool: block per graph, 256 threads, dword loads, 4-way row parallel
__global__ __launch_bounds__(256) void k_pool(
        const uint* __restrict__ h, const int* __restrict__ gptr,
        float* __restrict__ pooled) {
    __shared__ float2 part[256];
    int g = blockIdx.x, t = threadIdx.x;
    int d = t & 63, qq = t >> 6;
    int s = gptr[g], e = gptr[g + 1];
    float2 acc = make_float2(0.f, 0.f);
    for (int i = s + qq; i < e; i += 4) {
        uint x = h[(size_t)i * 64 + d];
        acc.x += bl(x); acc.y += bh(x);
    }
    part[t] = acc;
    __syncthreads();
    if (t < 64) {
        float2 p0 = part[t], p1 = part[t + 64], p2 = part[t + 128], p3 = part[t + 192];
        float inv = 1.f / fmaxf((float)(e - s), 1.f);
        ((float2*)(pooled + g * 128))[t] =
            make_float2((p0.x + p1.x + p2.x + p3.x) * inv,
                        (p0.y + p1.y + p2.y + p3.y) * inv);
    }
}

__global__ __launch_bounds__(64) void k_head(
        const float* __restrict__ pooled,
        const float* __restrict__ Wp1, const float* __restrict__ bp1,
        const float* __restrict__ Wp2, const float* __restrict__ bp2,
        float* __restrict__ scores) {
    __shared__ float p[128];
    __shared__ float t1[64];
    int g = blockIdx.x, t = threadIdx.x;
    p[t] = pooled[g * 128 + t];
    p[t + 64] = pooled[g * 128 + 64 + t];
    __syncthreads();
    float a = 0.f;
    for (int k = 0; k < 128; k++) a += p[k] * Wp1[k * 64 + t];
    t1[t] = fmaxf(a + bp1[t], 0.f);
    __syncthreads();
    if (t < NCLS) {
        float s = bp2[t];
        for (int k = 0; k < 64; k++) s += t1[k] * Wp2[k * NCLS + t];
        scores[g * NCLS + t] = s;
    }
}

extern "C" void kernel_launch(void* const* d_in, const int* in_sizes, int n_in,
                              void* d_out, int out_size, void* d_ws, size_t ws_size,
                              hipStream_t stream) {
    const float* hx  = (const float*)d_in[0];
    const int*   src = (const int*)d_in[1];
    const int*   dst = (const int*)d_in[2];
    const int*   gid = (const int*)d_in[3];
    const float* Ws[6], *bs[6];
    for (int l = 0; l < 6; l++) {
        Ws[l] = (const float*)d_in[5 + 2 * l];
        bs[l] = (const float*)d_in[6 + 2 * l];
    }
    const float* Wp1 = (const float*)d_in[17];
    const float* bp1 = (const float*)d_in[18];
    const float* Wp2 = (const float*)d_in[19];
    const float* bp2 = (const float*)d_in[20];
    float* scores = (float*)d_out;

    // ---- workspace layout (16B-aligned chunks) ----
    char* w = (char*)d_ws;
    ushort* xsA = (ushort*)w;     w += (size_t)NN * DF * 2;        // 16 MB
    ushort* xsB = (ushort*)w;     w += (size_t)NN * DF * 2;        // 16 MB
    ushort* Wt = (ushort*)w;      w += (size_t)6 * 128 * 128 * 2;  // 192 KB
    int* deg_in  = (int*)w;       w += NN * 4;
    int* deg_out = (int*)w;       w += NN * 4;
    int* cursor  = (int*)w;       w += NN * 4;
    int* rp      = (int*)w;       w += (NN + 1) * 4 + 12;
    int* colv    = (int*)w;       w += NE * 4;
    float* ns    = (float*)w;     w += NN * 4;
    float* ndst  = (float*)w;     w += NN * 4;
    int* gptr    = (int*)w;       w += (NG + 1) * 4 + 12;
    float* pooled = (float*)w;    w += NG * DF * 4;

    hipMemsetAsync(deg_in, 0, (size_t)NN * 4 * 3, stream);  // deg_in/deg_out/cursor

    k_degrees<<<NE / 256, 256, 0, stream>>>(src, dst, deg_out, deg_in);
    k_norms<<<NN / 256, 256, 0, stream>>>(deg_out, deg_in, ns, ndst);
    k_scan<<<1, 1024, 0, stream>>>(deg_in, rp);
    k_scatter<<<NE / 256, 256, 0, stream>>>(src, dst, rp, cursor, colv);
    k_scale<<<NN * 64 / 256, 256, 0, stream>>>(hx, ns, (uint*)xsA);
    for (int l = 0; l < 6; l++)
        k_wconv<<<64, 256, 0, stream>>>(Ws[l], Wt + (size_t)l * 128 * 128);

    ushort* cur = xsA;
    ushort* nxt = xsB;
    for (int l = 0; l < 6; l++) {
        k_fused<<<NN / 16, 128, 0, stream>>>(
            (const uint4*)cur, rp, colv, ndst, ns,
            (const uint4*)(Wt + (size_t)l * 128 * 128), bs[l],
            (l < 5) ? 1 : 0, nxt);
        ushort* tmp = cur; cur = nxt; nxt = tmp;
    }

    k_gptr<<<3, 256, 0, stream>>>(gid, gptr);
    k_pool<<<NG, 256, 0, stream>>>((const uint*)cur, gptr, pooled);
    k_head<<<NG, 64, 0, stream>>>(pooled, Wp1, bp1, Wp2, bp2, scores);
}

// Round 6
// 350.641 us; speedup vs baseline: 1.3674x; 1.3674x over previous
//
#include <hip/hip_runtime.h>
#include <hip/hip_bf16.h>

#define NN 65536
#define NE 524288
#define DF 128
#define NG 512
#define NCLS 10

typedef __bf16 bf16x8 __attribute__((ext_vector_type(8)));
typedef float f32x4 __attribute__((ext_vector_type(4)));
typedef ushort u16x8 __attribute__((ext_vector_type(8)));

__device__ __forceinline__ float bl(uint x) { return __uint_as_float(x << 16); }
__device__ __forceinline__ float bh(uint x) { return __uint_as_float(x & 0xffff0000u); }
__device__ __forceinline__ ushort f2b(float f) {
    uint u = __float_as_uint(f);
    return (ushort)((u + 0x7fffu + ((u >> 16) & 1u)) >> 16);  // RN-even
}

// ---------------- degree histograms (fire-and-forget atomics) ----------------
__global__ void k_degrees(const int* __restrict__ src, const int* __restrict__ dst,
                          int* __restrict__ deg_out, int* __restrict__ deg_in) {
    int e = blockIdx.x * blockDim.x + threadIdx.x;
    if (e < NE) {
        atomicAdd(&deg_out[src[e]], 1);
        atomicAdd(&deg_in[dst[e]], 1);
    }
}

__global__ void k_norms(const int* __restrict__ deg_out, const int* __restrict__ deg_in,
                        float* __restrict__ ns, float* __restrict__ nd,
                        int* __restrict__ colpad) {
    int v = blockIdx.x * blockDim.x + threadIdx.x;
    if (v < NN) {
        ns[v] = rsqrtf((float)max(deg_out[v], 1));
        nd[v] = rsqrtf((float)max(deg_in[v], 1));
    }
    if (v < 16) colpad[v] = 0;   // zero the col overshoot pad (safe gather target)
}

// exclusive scan of deg_in (NN ints) -> rp[0..NN]
__global__ void k_scan(const int* __restrict__ deg, int* __restrict__ rp) {
    __shared__ int tmp[1024];
    int t = threadIdx.x;
    int base = t * 64;
    int s = 0;
    for (int i = 0; i < 64; i++) s += deg[base + i];
    tmp[t] = s;
    __syncthreads();
    for (int off = 1; off < 1024; off <<= 1) {
        int v = (t >= off) ? tmp[t - off] : 0;
        __syncthreads();
        tmp[t] += v;
        __syncthreads();
    }
    int run = tmp[t] - s;
    for (int i = 0; i < 64; i++) {
        int d = deg[base + i];
        rp[base + i] = run;
        run += d;
    }
    if (t == 1023) rp[NN] = run;
}

__global__ void k_scatter(const int* __restrict__ src, const int* __restrict__ dst,
                          const int* __restrict__ rp, int* __restrict__ cursor,
                          int* __restrict__ col) {
    int e = blockIdx.x * blockDim.x + threadIdx.x;
    if (e < NE) {
        int d = dst[e];
        int p = atomicAdd(&cursor[d], 1);
        col[rp[d] + p] = src[e];
    }
}

// xs(bf16) = hx * norm_src; one dword (2 elems) per thread
__global__ void k_scale(const float* __restrict__ hx, const float* __restrict__ ns,
                        uint* __restrict__ xs) {
    int i = blockIdx.x * blockDim.x + threadIdx.x;  // over NN*64 dwords
    float2 v = ((const float2*)hx)[i];
    float s = ns[i >> 6];
    xs[i] = (uint)f2b(v.x * s) | ((uint)f2b(v.y * s) << 16);
}

// W (fp32 [k][n]) -> Wt (bf16 [n][k])
__global__ void k_wconv(const float* __restrict__ W, ushort* __restrict__ Wt) {
    int t = blockIdx.x * blockDim.x + threadIdx.x;  // 16384
    int n = t >> 7, k = t & 127;
    Wt[n * 128 + k] = f2b(W[k * 128 + n]);
}

// ---------------------------------------------------------------------------
// Fused: out = relu( (norm_dst * gather-sum(xs)) @ W + b ) * (scale? ns : 1)
// COALESCED-GATHER redesign (R5 post-mortem): the old layout had 16-way
// address divergence per load (16 scattered 64B lines/instr) — the per-CU
// divergent-line rate was the wall (R3 more-waves null, R4 sort null).
// Now ALL 64 lanes cooperate on ONE edge: lane l loads dword l of the src
// row (256B = 4 contiguous lines, 1 coalesced instr). The tile's 16 rows
// form one flat edge stream [rp[nb], rp[nb+16]) -> row boundaries are
// wave-uniform scalar control flow; col[j] is an s_load; degree divergence
// gone (wave work = sum of 16 degrees, not max). 4-batch x 4-edge pipeline
// = 16 dwords in flight (16 VGPRs payload -> no spill; R1/R5 lesson).
// Finished rows flush (2 floats/lane) to pad-132 LDS; MFMA reads fragments
// back. One wave per block, grid = NN/16 (R2's proven config).
// ---------------------------------------------------------------------------
#define ISSUE(x0, x1, x2, x3, J) { \
    x0 = X32[(size_t)col[(J)] * 64 + lane]; \
    x1 = X32[(size_t)col[(J) + 1] * 64 + lane]; \
    x2 = X32[(size_t)col[(J) + 2] * 64 + lane]; \
    x3 = X32[(size_t)col[(J) + 3] * 64 + lane]; }

#define FLUSHROWS(J) \
    while ((J) >= next_e && r < 15) { \
        Af[r * 132 + 2 * lane] = a0; Af[r * 132 + 2 * lane + 1] = a1; \
        a0 = 0.f; a1 = 0.f; r++; next_e = rp[nb + r + 1]; }

#define PROC1(xv, J) { FLUSHROWS(J) \
    if ((J) < E) { a0 += bl(xv); a1 += bh(xv); } }

__global__ __launch_bounds__(64, 2) void k_fused(
        const uint* __restrict__ X32,     // xs as dwords: node*64 + lane
        const int* __restrict__ rp, const int* __restrict__ col,
        const float* __restrict__ nd, const float* __restrict__ ns,
        const uint4* __restrict__ Wg,     // Wt bf16 [n][k] as uint4: n*16+chunk
        const float* __restrict__ b, int do_scale,
        ushort* __restrict__ out) {
    __shared__ float Af[16 * 132];        // 8.25 KB; +4 dword row pad (banks)
    int lane = threadIdx.x;
    int rr = lane & 15;     // fragment row / C col
    int q = lane >> 4;      // fragment k-quad / C row-quad
    int nb = blockIdx.x * 16;

    int S = rp[nb], E = rp[nb + 16];
    int r = 0;
    int next_e = rp[nb + 1];
    float a0 = 0.f, a1 = 0.f;

    // 4-deep pipeline of 4-edge batches: 16 coalesced dword-loads in flight
    uint xa0, xa1, xa2, xa3, xb0, xb1, xb2, xb3;
    uint xc0, xc1, xc2, xc3, xd0, xd1, xd2, xd3;
    int j = S;
    ISSUE(xa0, xa1, xa2, xa3, j)
    ISSUE(xb0, xb1, xb2, xb3, j + 4)
    ISSUE(xc0, xc1, xc2, xc3, j + 8)
    ISSUE(xd0, xd1, xd2, xd3, j + 12)
    for (; j + 16 <= E; j += 16) {
        PROC1(xa0, j)      PROC1(xa1, j + 1)  PROC1(xa2, j + 2)  PROC1(xa3, j + 3)
        ISSUE(xa0, xa1, xa2, xa3, j + 16)
        PROC1(xb0, j + 4)  PROC1(xb1, j + 5)  PROC1(xb2, j + 6)  PROC1(xb3, j + 7)
        ISSUE(xb0, xb1, xb2, xb3, j + 20)
        PROC1(xc0, j + 8)  PROC1(xc1, j + 9)  PROC1(xc2, j + 10) PROC1(xc3, j + 11)
        ISSUE(xc0, xc1, xc2, xc3, j + 24)
        PROC1(xd0, j + 12) PROC1(xd1, j + 13) PROC1(xd2, j + 14) PROC1(xd3, j + 15)
        ISSUE(xd0, xd1, xd2, xd3, j + 28)
    }
    // tail: remaining < 16 edges already resident in batches A..D (guarded)
    PROC1(xa0, j)      PROC1(xa1, j + 1)  PROC1(xa2, j + 2)  PROC1(xa3, j + 3)
    PROC1(xb0, j + 4)  PROC1(xb1, j + 5)  PROC1(xb2, j + 6)  PROC1(xb3, j + 7)
    PROC1(xc0, j + 8)  PROC1(xc1, j + 9)  PROC1(xc2, j + 10) PROC1(xc3, j + 11)
    PROC1(xd0, j + 12) PROC1(xd1, j + 13) PROC1(xd2, j + 14) PROC1(xd3, j + 15)
    // drain: flush current row and any remaining empty rows
    for (; r < 16; r++) {
        Af[r * 132 + 2 * lane] = a0;
        Af[r * 132 + 2 * lane + 1] = a1;
        a0 = 0.f; a1 = 0.f;
    }

    // A-fragments from LDS (scale by norm_dst), then MFMA (same as R2)
    float ndv = nd[nb + rr];
    bf16x8 afr[4];
    #pragma unroll
    for (int ks = 0; ks < 4; ks++) {
        const f32x4* Afv = (const f32x4*)&Af[rr * 132 + ks * 32 + q * 8];
        f32x4 v0 = Afv[0], v1 = Afv[1];
        union { u16x8 u; bf16x8 f; } cv;
        cv.u[0] = f2b(v0[0] * ndv); cv.u[1] = f2b(v0[1] * ndv);
        cv.u[2] = f2b(v0[2] * ndv); cv.u[3] = f2b(v0[3] * ndv);
        cv.u[4] = f2b(v1[0] * ndv); cv.u[5] = f2b(v1[1] * ndv);
        cv.u[6] = f2b(v1[2] * ndv); cv.u[7] = f2b(v1[3] * ndv);
        afr[ks] = cv.f;
    }

    f32x4 cacc[8] = {};
    #pragma unroll
    for (int ks = 0; ks < 4; ks++) {
        #pragma unroll
        for (int ni = 0; ni < 8; ni++) {
            union { uint4 u; bf16x8 f; } bw;
            bw.u = Wg[(size_t)(ni * 16 + rr) * 16 + ks * 4 + q];
            cacc[ni] = __builtin_amdgcn_mfma_f32_16x16x32_bf16(
                afr[ks], bw.f, cacc[ni], 0, 0, 0);
        }
    }

    // epilogue: bias + relu + (ns fold) -> bf16, staged in LDS (reuse Af)
    ushort* Cs = (ushort*)Af;             // [16][128]
    float sc4[4];
    #pragma unroll
    for (int rg = 0; rg < 4; rg++)
        sc4[rg] = do_scale ? ns[nb + q * 4 + rg] : 1.f;
    #pragma unroll
    for (int ni = 0; ni < 8; ni++) {
        int c = ni * 16 + rr;
        float bb = b[c];
        #pragma unroll
        for (int rg = 0; rg < 4; rg++) {
            float v = fmaxf(cacc[ni][rg] + bb, 0.f) * sc4[rg];
            Cs[(q * 4 + rg) * 128 + c] = f2b(v);
        }
    }
    const uint4* Cs4 = (const uint4*)Cs;
    uint4* Og = (uint4*)(out + (size_t)nb * 128);
    #pragma unroll
    for (int it = 0; it < 4; it++)
        Og[it * 64 + lane] = Cs4[it * 64 + lane];
}

// graph row pointers via binary search on sorted graph_id
__global__ void k_gptr(const int* __restrict__ gid, int* __restrict__ gptr) {
    int g = blockIdx.x * blockDim.x + threadIdx.x;
    if (g <= NG) {
        int lo = 0, hi = NN;
        while (lo < hi) {
            int mid = (lo + hi) >> 1;
            if (gid[mid] < g) lo = mid + 1; else hi = mid;
        }
        gptr[g] = lo;
    }
}

// mean-pool: block per graph, 256 threads, dword loads, 4-way row parallel
__global__ __launch_bounds__(256) void k_pool(
        const uint* __restrict__ h, const int* __restrict__ gptr,
        float* __restrict__ pooled) {
    __shared__ float2 part[256];
    int g = blockIdx.x, t = threadIdx.x;
    int d = t & 63, qq = t >> 6;
    int s = gptr[g], e = gptr[g + 1];
    float2 acc = make_float2(0.f, 0.f);
    for (int i = s + qq; i < e; i += 4) {
        uint x = h[(size_t)i * 64 + d];
        acc.x += bl(x); acc.y += bh(x);
    }
    part[t] = acc;
    __syncthreads();
    if (t < 64) {
        float2 p0 = part[t], p1 = part[t + 64], p2 = part[t + 128], p3 = part[t + 192];
        float inv = 1.f / fmaxf((float)(e - s), 1.f);
        ((float2*)(pooled + g * 128))[t] =
            make_float2((p0.x + p1.x + p2.x + p3.x) * inv,
                        (p0.y + p1.y + p2.y + p3.y) * inv);
    }
}

__global__ __launch_bounds__(64) void k_head(
        const float* __restrict__ pooled,
        const float* __restrict__ Wp1, const float* __restrict__ bp1,
        const float* __restrict__ Wp2, const float* __restrict__ bp2,
        float* __restrict__ scores) {
    __shared__ float p[128];
    __shared__ float t1[64];
    int g = blockIdx.x, t = threadIdx.x;
    p[t] = pooled[g * 128 + t];
    p[t + 64] = pooled[g * 128 + 64 + t];
    __syncthreads();
    float a = 0.f;
    for (int k = 0; k < 128; k++) a += p[k] * Wp1[k * 64 + t];
    t1[t] = fmaxf(a + bp1[t], 0.f);
    __syncthreads();
    if (t < NCLS) {
        float s = bp2[t];
        for (int k = 0; k < 64; k++) s += t1[k] * Wp2[k * NCLS + t];
        scores[g * NCLS + t] = s;
    }
}

extern "C" void kernel_launch(void* const* d_in, const int* in_sizes, int n_in,
                              void* d_out, int out_size, void* d_ws, size_t ws_size,
                              hipStream_t stream) {
    const float* hx  = (const float*)d_in[0];
    const int*   src = (const int*)d_in[1];
    const int*   dst = (const int*)d_in[2];
    const int*   gid = (const int*)d_in[3];
    const float* Ws[6], *bs[6];
    for (int l = 0; l < 6; l++) {
        Ws[l] = (const float*)d_in[5 + 2 * l];
        bs[l] = (const float*)d_in[6 + 2 * l];
    }
    const float* Wp1 = (const float*)d_in[17];
    const float* bp1 = (const float*)d_in[18];
    const float* Wp2 = (const float*)d_in[19];
    const float* bp2 = (const float*)d_in[20];
    float* scores = (float*)d_out;

    // ---- workspace layout (16B-aligned chunks) ----
    char* w = (char*)d_ws;
    ushort* xsA = (ushort*)w;     w += (size_t)NN * DF * 2;        // 16 MB
    ushort* xsB = (ushort*)w;     w += (size_t)NN * DF * 2;        // 16 MB
    ushort* Wt = (ushort*)w;      w += (size_t)6 * 128 * 128 * 2;  // 192 KB
    int* deg_in  = (int*)w;       w += NN * 4;
    int* deg_out = (int*)w;       w += NN * 4;
    int* cursor  = (int*)w;       w += NN * 4;
    int* rp      = (int*)w;       w += (NN + 1) * 4 + 12;
    int* colv    = (int*)w;       w += (NE + 16) * 4;              // +16 pad
    float* ns    = (float*)w;     w += NN * 4;
    float* ndst  = (float*)w;     w += NN * 4;
    int* gptr    = (int*)w;       w += (NG + 1) * 4 + 12;
    float* pooled = (float*)w;    w += NG * DF * 4;

    hipMemsetAsync(deg_in, 0, (size_t)NN * 4 * 3, stream);  // deg_in/deg_out/cursor

    k_degrees<<<NE / 256, 256, 0, stream>>>(src, dst, deg_out, deg_in);
    k_norms<<<NN / 256, 256, 0, stream>>>(deg_out, deg_in, ns, ndst, colv + NE);
    k_scan<<<1, 1024, 0, stream>>>(deg_in, rp);
    k_scatter<<<NE / 256, 256, 0, stream>>>(src, dst, rp, cursor, colv);
    k_scale<<<NN * 64 / 256, 256, 0, stream>>>(hx, ns, (uint*)xsA);
    for (int l = 0; l < 6; l++)
        k_wconv<<<64, 256, 0, stream>>>(Ws[l], Wt + (size_t)l * 128 * 128);

    ushort* cur = xsA;
    ushort* nxt = xsB;
    for (int l = 0; l < 6; l++) {
        k_fused<<<NN / 16, 64, 0, stream>>>(
            (const uint*)cur, rp, colv, ndst, ns,
            (const uint4*)(Wt + (size_t)l * 128 * 128), bs[l],
            (l < 5) ? 1 : 0, nxt);
        ushort* tmp = cur; cur = nxt; nxt = tmp;
    }

    k_gptr<<<3, 256, 0, stream>>>(gid, gptr);
    k_pool<<<NG, 256, 0, stream>>>((const uint*)cur, gptr, pooled);
    k_head<<<NG, 64, 0, stream>>>(pooled, Wp1, bp1, Wp2, bp2, scores);
}

// Round 7
// 294.776 us; speedup vs baseline: 1.6265x; 1.1895x over previous
//
#include <hip/hip_runtime.h>
#include <hip/hip_bf16.h>

#define NN 65536
#define NE 524288
#define DF 128
#define NG 512
#define NCLS 10
#define NBLK 256
#define EPB (NE / NBLK)    // 2048 edges per block
#define EPT (EPB / 256)    // 8 edges per thread

typedef __bf16 bf16x8 __attribute__((ext_vector_type(8)));
typedef float f32x4 __attribute__((ext_vector_type(4)));
typedef ushort u16x8 __attribute__((ext_vector_type(8)));

__device__ __forceinline__ float bl(uint x) { return __uint_as_float(x << 16); }
__device__ __forceinline__ float bh(uint x) { return __uint_as_float(x & 0xffff0000u); }
__device__ __forceinline__ ushort f2b(float f) {
    uint u = __float_as_uint(f);
    return (ushort)((u + 0x7fffu + ((u >> 16) & 1u)) >> 16);  // RN-even
}

// ---------------------------------------------------------------------------
// Atomic-free CSR build (R6 post-mortem: global atomics write ~64B/op through
// to HBM — k_degrees was 42 us with 32.7 MB WRITE_SIZE = NE*64B. The whole
// degree/scan/scatter chain is replaced by a 2-level bucket sort using only
// LDS atomics + precomputed placement bases.)
// ---------------------------------------------------------------------------

// K1: per-block 256-bin histograms of dst>>8 and src>>8
__global__ __launch_bounds__(256) void k_hist(
        const int* __restrict__ src, const int* __restrict__ dst,
        int* __restrict__ Md, int* __restrict__ Ms) {
    __shared__ int hd[256], hs[256];
    int t = threadIdx.x, b = blockIdx.x;
    hd[t] = 0; hs[t] = 0;
    __syncthreads();
    int base = b * EPB;
    for (int k = 0; k < EPT; k++) {
        int e = base + k * 256 + t;
        atomicAdd(&hd[dst[e] >> 8], 1);
        atomicAdd(&hs[src[e] >> 8], 1);
    }
    __syncthreads();
    Md[b * 256 + t] = hd[t];
    Ms[b * 256 + t] = hs[t];
}

// K2 (1 block): column scans of both matrices -> per-(block,bin) bases (excl
// of bucket base) + bucket base arrays
__global__ __launch_bounds__(256) void k_colscan(
        const int* __restrict__ Md, const int* __restrict__ Ms,
        int* __restrict__ Bd, int* __restrict__ Bs,
        int* __restrict__ bbd, int* __restrict__ bbs) {
    __shared__ int tot[256];
    int t = threadIdx.x;
    int run = 0;
    for (int b = 0; b < NBLK; b++) { Bd[b * 256 + t] = run; run += Md[b * 256 + t]; }
    tot[t] = run;
    __syncthreads();
    if (t == 0) { int r = 0; for (int i = 0; i < 256; i++) { int c = tot[i]; tot[i] = r; r += c; } }
    __syncthreads();
    bbd[t] = tot[t];
    if (t == 0) bbd[256] = NE;
    __syncthreads();
    run = 0;
    for (int b = 0; b < NBLK; b++) { Bs[b * 256 + t] = run; run += Ms[b * 256 + t]; }
    tot[t] = run;
    __syncthreads();
    if (t == 0) { int r = 0; for (int i = 0; i < 256; i++) { int c = tot[i]; tot[i] = r; r += c; } }
    __syncthreads();
    bbs[t] = tot[t];
    if (t == 0) bbs[256] = NE;
}

// K3: atomic-free placement into buckets (LDS cursors seeded from bases)
__global__ __launch_bounds__(256) void k_place(
        const int* __restrict__ src, const int* __restrict__ dst,
        const int* __restrict__ Bd, const int* __restrict__ bbd,
        const int* __restrict__ Bs, const int* __restrict__ bbs,
        uint* __restrict__ drec, ushort* __restrict__ srec) {
    __shared__ int cd[256], cs[256];
    int t = threadIdx.x, b = blockIdx.x;
    cd[t] = bbd[t] + Bd[b * 256 + t];
    cs[t] = bbs[t] + Bs[b * 256 + t];
    __syncthreads();
    int base = b * EPB;
    for (int k = 0; k < EPT; k++) {
        int e = base + k * 256 + t;
        int d = dst[e], s = src[e];
        int pd = atomicAdd(&cd[d >> 8], 1);           // LDS atomic
        drec[pd] = ((uint)s << 8) | (uint)(d & 255);
        int ps = atomicAdd(&cs[s >> 8], 1);           // LDS atomic
        srec[ps] = (ushort)(s & 255);
    }
}

// K4: one block per dst-bucket: LDS counting sort by low byte ->
// col (sorted src), rp (bucket base + scan), nd (rsqrt deg_in)
__global__ __launch_bounds__(256) void k_bsort(
        const uint* __restrict__ drec, const int* __restrict__ bbd,
        int* __restrict__ col, int* __restrict__ rp, float* __restrict__ nd) {
    __shared__ int hist[256], cur[256], sc[256];
    __shared__ uint recs[4096];
    __shared__ int colst[4096];
    int t = threadIdx.x, b = blockIdx.x;
    int s0 = bbd[b];
    int n = min(bbd[b + 1] - s0, 4096);   // mean 2048, sigma 45 -> 4096 is 45-sigma safe
    hist[t] = 0;
    __syncthreads();
    for (int i = t; i < n; i += 256) {
        uint rc = drec[s0 + i];
        recs[i] = rc;
        atomicAdd(&hist[rc & 255u], 1);
    }
    __syncthreads();
    int v = hist[t];
    sc[t] = v;
    __syncthreads();
    for (int off = 1; off < 256; off <<= 1) {
        int x = (t >= off) ? sc[t - off] : 0;
        __syncthreads();
        sc[t] += x;
        __syncthreads();
    }
    int excl = sc[t] - v;
    rp[b * 256 + t] = s0 + excl;
    nd[b * 256 + t] = rsqrtf((float)max(v, 1));
    cur[t] = excl;
    __syncthreads();
    for (int i = t; i < n; i += 256) {
        uint rc = recs[i];
        int p = atomicAdd(&cur[rc & 255u], 1);        // LDS atomic
        colst[p] = (int)(rc >> 8);
    }
    __syncthreads();
    for (int i = t; i < n; i += 256) col[s0 + i] = colst[i];
    if (b == 0) {
        if (t == 0) rp[NN] = NE;
        if (t < 16) col[NE + t] = 0;   // zero overshoot pad (safe gather target)
    }
}

// K5: one block per src-bucket: LDS histogram -> ns (rsqrt deg_out)
__global__ __launch_bounds__(256) void k_shist(
        const ushort* __restrict__ srec, const int* __restrict__ bbs,
        float* __restrict__ ns) {
    __shared__ int hist[256];
    int t = threadIdx.x, b = blockIdx.x;
    hist[t] = 0;
    __syncthreads();
    int s0 = bbs[b], e0 = bbs[b + 1];
    for (int i = s0 + t; i < e0; i += 256)
        atomicAdd(&hist[srec[i] & 255], 1);
    __syncthreads();
    ns[b * 256 + t] = rsqrtf((float)max(hist[t], 1));
}

// xs(bf16) = hx * norm_src; one dword (2 elems) per thread
__global__ void k_scale(const float* __restrict__ hx, const float* __restrict__ ns,
                        uint* __restrict__ xs) {
    int i = blockIdx.x * blockDim.x + threadIdx.x;  // over NN*64 dwords
    float2 v = ((const float2*)hx)[i];
    float s = ns[i >> 6];
    xs[i] = (uint)f2b(v.x * s) | ((uint)f2b(v.y * s) << 16);
}

// W (fp32 [k][n]) -> Wt (bf16 [n][k])
__global__ void k_wconv(const float* __restrict__ W, ushort* __restrict__ Wt) {
    int t = blockIdx.x * blockDim.x + threadIdx.x;  // 16384
    int n = t >> 7, k = t & 127;
    Wt[n * 128 + k] = f2b(W[k * 128 + n]);
}

// ---------------------------------------------------------------------------
// Fused conv layer (unchanged from R6 — coalesced cooperative gather):
// all 64 lanes cooperate on ONE edge (lane l loads dword l of the src row,
// 256B coalesced); flat edge stream per 16-row tile, wave-uniform control;
// 4-batch x 4-edge pipeline (16 dwords in flight, no spill);
// rows flush to pad-132 LDS; MFMA + epilogue as proven in R2.
// ---------------------------------------------------------------------------
#define ISSUE(x0, x1, x2, x3, J) { \
    x0 = X32[(size_t)col[(J)] * 64 + lane]; \
    x1 = X32[(size_t)col[(J) + 1] * 64 + lane]; \
    x2 = X32[(size_t)col[(J) + 2] * 64 + lane]; \
    x3 = X32[(size_t)col[(J) + 3] * 64 + lane]; }

#define FLUSHROWS(J) \
    while ((J) >= next_e && r < 15) { \
        Af[r * 132 + 2 * lane] = a0; Af[r * 132 + 2 * lane + 1] = a1; \
        a0 = 0.f; a1 = 0.f; r++; next_e = rp[nb + r + 1]; }

#define PROC1(xv, J) { FLUSHROWS(J) \
    if ((J) < E) { a0 += bl(xv); a1 += bh(xv); } }

__global__ __launch_bounds__(64, 2) void k_fused(
        const uint* __restrict__ X32,     // xs as dwords: node*64 + lane
        const int* __restrict__ rp, const int* __restrict__ col,
        const float* __restrict__ nd, const float* __restrict__ ns,
        const uint4* __restrict__ Wg,     // Wt bf16 [n][k] as uint4: n*16+chunk
        const float* __restrict__ b, int do_scale,
        ushort* __restrict__ out) {
    __shared__ float Af[16 * 132];        // 8.25 KB; +4 dword row pad (banks)
    int lane = threadIdx.x;
    int rr = lane & 15;     // fragment row / C col
    int q = lane >> 4;      // fragment k-quad / C row-quad
    int nb = blockIdx.x * 16;

    int S = rp[nb], E = rp[nb + 16];
    int r = 0;
    int next_e = rp[nb + 1];
    float a0 = 0.f, a1 = 0.f;

    uint xa0, xa1, xa2, xa3, xb0, xb1, xb2, xb3;
    uint xc0, xc1, xc2, xc3, xd0, xd1, xd2, xd3;
    int j = S;
    ISSUE(xa0, xa1, xa2, xa3, j)
    ISSUE(xb0, xb1, xb2, xb3, j + 4)
    ISSUE(xc0, xc1, xc2, xc3, j + 8)
    ISSUE(xd0, xd1, xd2, xd3, j + 12)
    for (; j + 16 <= E; j += 16) {
        PROC1(xa0, j)      PROC1(xa1, j + 1)  PROC1(xa2, j + 2)  PROC1(xa3, j + 3)
        ISSUE(xa0, xa1, xa2, xa3, j + 16)
        PROC1(xb0, j + 4)  PROC1(xb1, j + 5)  PROC1(xb2, j + 6)  PROC1(xb3, j + 7)
        ISSUE(xb0, xb1, xb2, xb3, j + 20)
        PROC1(xc0, j + 8)  PROC1(xc1, j + 9)  PROC1(xc2, j + 10) PROC1(xc3, j + 11)
        ISSUE(xc0, xc1, xc2, xc3, j + 24)
        PROC1(xd0, j + 12) PROC1(xd1, j + 13) PROC1(xd2, j + 14) PROC1(xd3, j + 15)
        ISSUE(xd0, xd1, xd2, xd3, j + 28)
    }
    PROC1(xa0, j)      PROC1(xa1, j + 1)  PROC1(xa2, j + 2)  PROC1(xa3, j + 3)
    PROC1(xb0, j + 4)  PROC1(xb1, j + 5)  PROC1(xb2, j + 6)  PROC1(xb3, j + 7)
    PROC1(xc0, j + 8)  PROC1(xc1, j + 9)  PROC1(xc2, j + 10) PROC1(xc3, j + 11)
    PROC1(xd0, j + 12) PROC1(xd1, j + 13) PROC1(xd2, j + 14) PROC1(xd3, j + 15)
    for (; r < 16; r++) {
        Af[r * 132 + 2 * lane] = a0;
        Af[r * 132 + 2 * lane + 1] = a1;
        a0 = 0.f; a1 = 0.f;
    }

    // A-fragments from LDS (scale by norm_dst), then MFMA
    float ndv = nd[nb + rr];
    bf16x8 afr[4];
    #pragma unroll
    for (int ks = 0; ks < 4; ks++) {
        const f32x4* Afv = (const f32x4*)&Af[rr * 132 + ks * 32 + q * 8];
        f32x4 v0 = Afv[0], v1 = Afv[1];
        union { u16x8 u; bf16x8 f; } cv;
        cv.u[0] = f2b(v0[0] * ndv); cv.u[1] = f2b(v0[1] * ndv);
        cv.u[2] = f2b(v0[2] * ndv); cv.u[3] = f2b(v0[3] * ndv);
        cv.u[4] = f2b(v1[0] * ndv); cv.u[5] = f2b(v1[1] * ndv);
        cv.u[6] = f2b(v1[2] * ndv); cv.u[7] = f2b(v1[3] * ndv);
        afr[ks] = cv.f;
    }

    f32x4 cacc[8] = {};
    #pragma unroll
    for (int ks = 0; ks < 4; ks++) {
        #pragma unroll
        for (int ni = 0; ni < 8; ni++) {
            union { uint4 u; bf16x8 f; } bw;
            bw.u = Wg[(size_t)(ni * 16 + rr) * 16 + ks * 4 + q];
            cacc[ni] = __builtin_amdgcn_mfma_f32_16x16x32_bf16(
                afr[ks], bw.f, cacc[ni], 0, 0, 0);
        }
    }

    // epilogue: bias + relu + (ns fold) -> bf16, staged in LDS (reuse Af)
    ushort* Cs = (ushort*)Af;             // [16][128]
    float sc4[4];
    #pragma unroll
    for (int rg = 0; rg < 4; rg++)
        sc4[rg] = do_scale ? ns[nb + q * 4 + rg] : 1.f;
    #pragma unroll
    for (int ni = 0; ni < 8; ni++) {
        int c = ni * 16 + rr;
        float bb = b[c];
        #pragma unroll
        for (int rg = 0; rg < 4; rg++) {
            float v = fmaxf(cacc[ni][rg] + bb, 0.f) * sc4[rg];
            Cs[(q * 4 + rg) * 128 + c] = f2b(v);
        }
    }
    const uint4* Cs4 = (const uint4*)Cs;
    uint4* Og = (uint4*)(out + (size_t)nb * 128);
    #pragma unroll
    for (int it = 0; it < 4; it++)
        Og[it * 64 + lane] = Cs4[it * 64 + lane];
}

// graph row pointers via binary search on sorted graph_id
__global__ void k_gptr(const int* __restrict__ gid, int* __restrict__ gptr) {
    int g = blockIdx.x * blockDim.x + threadIdx.x;
    if (g <= NG) {
        int lo = 0, hi = NN;
        while (lo < hi) {
            int mid = (lo + hi) >> 1;
            if (gid[mid] < g) lo = mid + 1; else hi = mid;
        }
        gptr[g] = lo;
    }
}

// mean-pool: block per graph, 256 threads, dword loads, 4-way row parallel
__global__ __launch_bounds__(256) void k_pool(
        const uint* __restrict__ h, const int* __restrict__ gptr,
        float* __restrict__ pooled) {
    __shared__ float2 part[256];
    int g = blockIdx.x, t = threadIdx.x;
    int d = t & 63, qq = t >> 6;
    int s = gptr[g], e = gptr[g + 1];
    float2 acc = make_float2(0.f, 0.f);
    for (int i = s + qq; i < e; i += 4) {
        uint x = h[(size_t)i * 64 + d];
        acc.x += bl(x); acc.y += bh(x);
    }
    part[t] = acc;
    __syncthreads();
    if (t < 64) {
        float2 p0 = part[t], p1 = part[t + 64], p2 = part[t + 128], p3 = part[t + 192];
        float inv = 1.f / fmaxf((float)(e - s), 1.f);
        ((float2*)(pooled + g * 128))[t] =
            make_float2((p0.x + p1.x + p2.x + p3.x) * inv,
                        (p0.y + p1.y + p2.y + p3.y) * inv);
    }
}

__global__ __launch_bounds__(64) void k_head(
        const float* __restrict__ pooled,
        const float* __restrict__ Wp1, const float* __restrict__ bp1,
        const float* __restrict__ Wp2, const float* __restrict__ bp2,
        float* __restrict__ scores) {
    __shared__ float p[128];
    __shared__ float t1[64];
    int g = blockIdx.x, t = threadIdx.x;
    p[t] = pooled[g * 128 + t];
    p[t + 64] = pooled[g * 128 + 64 + t];
    __syncthreads();
    float a = 0.f;
    for (int k = 0; k < 128; k++) a += p[k] * Wp1[k * 64 + t];
    t1[t] = fmaxf(a + bp1[t], 0.f);
    __syncthreads();
    if (t < NCLS) {
        float s = bp2[t];
        for (int k = 0; k < 64; k++) s += t1[k] * Wp2[k * NCLS + t];
        scores[g * NCLS + t] = s;
    }
}

extern "C" void kernel_launch(void* const* d_in, const int* in_sizes, int n_in,
                              void* d_out, int out_size, void* d_ws, size_t ws_size,
                              hipStream_t stream) {
    const float* hx  = (const float*)d_in[0];
    const int*   src = (const int*)d_in[1];
    const int*   dst = (const int*)d_in[2];
    const int*   gid = (const int*)d_in[3];
    const float* Ws[6], *bs[6];
    for (int l = 0; l < 6; l++) {
        Ws[l] = (const float*)d_in[5 + 2 * l];
        bs[l] = (const float*)d_in[6 + 2 * l];
    }
    const float* Wp1 = (const float*)d_in[17];
    const float* bp1 = (const float*)d_in[18];
    const float* Wp2 = (const float*)d_in[19];
    const float* bp2 = (const float*)d_in[20];
    float* scores = (float*)d_out;

    // ---- workspace layout (16B-aligned chunks) ----
    char* w = (char*)d_ws;
    ushort* xsA = (ushort*)w;     w += (size_t)NN * DF * 2;        // 16 MB
    ushort* xsB = (ushort*)w;     w += (size_t)NN * DF * 2;        // 16 MB
    ushort* Wt = (ushort*)w;      w += (size_t)6 * 128 * 128 * 2;  // 192 KB
    int* Md   = (int*)w;          w += 256 * 256 * 4;              // 256 KB
    int* Ms   = (int*)w;          w += 256 * 256 * 4;
    int* Bd   = (int*)w;          w += 256 * 256 * 4;
    int* Bs   = (int*)w;          w += 256 * 256 * 4;
    int* bbd  = (int*)w;          w += 257 * 4 + 12;
    int* bbs  = (int*)w;          w += 257 * 4 + 12;
    int* rp   = (int*)w;          w += (NN + 1) * 4 + 12;
    int* colv = (int*)w;          w += (NE + 16) * 4;              // +16 pad
    float* ns   = (float*)w;      w += NN * 4;
    float* ndst = (float*)w;      w += NN * 4;
    int* gptr   = (int*)w;        w += (NG + 1) * 4 + 12;
    float* pooled = (float*)w;    w += NG * DF * 4;
    // bucket records alias the head of xsB (dead until k_fused layer 0,
    // which launches after k_bsort/k_shist consumed them — stream-ordered)
    uint*   drec = (uint*)xsB;                          // 2 MB
    ushort* srec = (ushort*)((char*)xsB + (size_t)NE * 4);  // 1 MB

    k_hist<<<NBLK, 256, 0, stream>>>(src, dst, Md, Ms);
    k_colscan<<<1, 256, 0, stream>>>(Md, Ms, Bd, Bs, bbd, bbs);
    k_place<<<NBLK, 256, 0, stream>>>(src, dst, Bd, bbd, Bs, bbs, drec, srec);
    k_bsort<<<NBLK, 256, 0, stream>>>(drec, bbd, colv, rp, ndst);
    k_shist<<<NBLK, 256, 0, stream>>>(srec, bbs, ns);
    k_scale<<<NN * 64 / 256, 256, 0, stream>>>(hx, ns, (uint*)xsA);
    for (int l = 0; l < 6; l++)
        k_wconv<<<64, 256, 0, stream>>>(Ws[l], Wt + (size_t)l * 128 * 128);

    ushort* cur = xsA;
    ushort* nxt = xsB;
    for (int l = 0; l < 6; l++) {
        k_fused<<<NN / 16, 64, 0, stream>>>(
            (const uint*)cur, rp, colv, ndst, ns,
            (const uint4*)(Wt + (size_t)l * 128 * 128), bs[l],
            (l < 5) ? 1 : 0, nxt);
        ushort* tmp = cur; cur = nxt; nxt = tmp;
    }

    k_gptr<<<3, 256, 0, stream>>>(gid, gptr);
    k_pool<<<NG, 256, 0, stream>>>((const uint*)cur, gptr, pooled);
    k_head<<<NG, 64, 0, stream>>>(pooled, Wp1, bp1, Wp2, bp2, scores);
}

// Round 8
// 285.861 us; speedup vs baseline: 1.6773x; 1.0312x over previous
//
#include <hip/hip_runtime.h>
#include <hip/hip_bf16.h>

#define NN 65536
#define NE 524288
#define DF 128
#define NG 512
#define NCLS 10
#define NBLK 256
#define EPB (NE / NBLK)    // 2048 edges per block
#define EPT (EPB / 256)    // 8 edges per thread

typedef __bf16 bf16x8 __attribute__((ext_vector_type(8)));
typedef float f32x4 __attribute__((ext_vector_type(4)));
typedef ushort u16x8 __attribute__((ext_vector_type(8)));

__device__ __forceinline__ float bl(uint x) { return __uint_as_float(x << 16); }
__device__ __forceinline__ float bh(uint x) { return __uint_as_float(x & 0xffff0000u); }
__device__ __forceinline__ ushort f2b(float f) {
    uint u = __float_as_uint(f);
    return (ushort)((u + 0x7fffu + ((u >> 16) & 1u)) >> 16);  // RN-even
}

// ---------------------------------------------------------------------------
// Atomic-free CSR build (R6: global atomics write ~64B/op through to HBM).
// 2-level bucket sort using only LDS atomics + precomputed placement bases.
// ---------------------------------------------------------------------------

// K1: per-block 256-bin histograms of dst>>8 and src>>8
__global__ __launch_bounds__(256) void k_hist(
        const int* __restrict__ src, const int* __restrict__ dst,
        int* __restrict__ Md, int* __restrict__ Ms) {
    __shared__ int hd[256], hs[256];
    int t = threadIdx.x, b = blockIdx.x;
    hd[t] = 0; hs[t] = 0;
    __syncthreads();
    int base = b * EPB;
    for (int k = 0; k < EPT; k++) {
        int e = base + k * 256 + t;
        atomicAdd(&hd[dst[e] >> 8], 1);
        atomicAdd(&hs[src[e] >> 8], 1);
    }
    __syncthreads();
    Md[b * 256 + t] = hd[t];
    Ms[b * 256 + t] = hs[t];
}

// K2 (2 blocks: blk0=dst, blk1=src): column scan -> per-(block,bin) bases +
// bucket bases
__global__ __launch_bounds__(256) void k_colscan(
        const int* __restrict__ Md, const int* __restrict__ Ms,
        int* __restrict__ Bd, int* __restrict__ Bs,
        int* __restrict__ bbd, int* __restrict__ bbs) {
    __shared__ int tot[256];
    int t = threadIdx.x;
    const int* M = blockIdx.x ? Ms : Md;
    int* B = blockIdx.x ? Bs : Bd;
    int* bb = blockIdx.x ? bbs : bbd;
    int run = 0;
    #pragma unroll 8
    for (int b = 0; b < NBLK; b++) { B[b * 256 + t] = run; run += M[b * 256 + t]; }
    tot[t] = run;
    __syncthreads();
    if (t == 0) { int r = 0; for (int i = 0; i < 256; i++) { int c = tot[i]; tot[i] = r; r += c; } }
    __syncthreads();
    bb[t] = tot[t];
    if (t == 0) bb[256] = NE;
}

// K3: atomic-free placement into buckets (LDS cursors seeded from bases)
__global__ __launch_bounds__(256) void k_place(
        const int* __restrict__ src, const int* __restrict__ dst,
        const int* __restrict__ Bd, const int* __restrict__ bbd,
        const int* __restrict__ Bs, const int* __restrict__ bbs,
        uint* __restrict__ drec, ushort* __restrict__ srec) {
    __shared__ int cd[256], cs[256];
    int t = threadIdx.x, b = blockIdx.x;
    cd[t] = bbd[t] + Bd[b * 256 + t];
    cs[t] = bbs[t] + Bs[b * 256 + t];
    __syncthreads();
    int base = b * EPB;
    for (int k = 0; k < EPT; k++) {
        int e = base + k * 256 + t;
        int d = dst[e], s = src[e];
        int pd = atomicAdd(&cd[d >> 8], 1);           // LDS atomic
        drec[pd] = ((uint)s << 8) | (uint)(d & 255);
        int ps = atomicAdd(&cs[s >> 8], 1);           // LDS atomic
        srec[ps] = (ushort)(s & 255);
    }
}

// K4: one block per dst-bucket: LDS counting sort by low byte ->
// col (sorted src), rp (bucket base + scan), nd (rsqrt deg_in)
__global__ __launch_bounds__(256) void k_bsort(
        const uint* __restrict__ drec, const int* __restrict__ bbd,
        int* __restrict__ col, int* __restrict__ rp, float* __restrict__ nd) {
    __shared__ int hist[256], cur[256], sc[256];
    __shared__ uint recs[4096];
    __shared__ int colst[4096];
    int t = threadIdx.x, b = blockIdx.x;
    int s0 = bbd[b];
    int n = min(bbd[b + 1] - s0, 4096);
    hist[t] = 0;
    __syncthreads();
    for (int i = t; i < n; i += 256) {
        uint rc = drec[s0 + i];
        recs[i] = rc;
        atomicAdd(&hist[rc & 255u], 1);
    }
    __syncthreads();
    int v = hist[t];
    sc[t] = v;
    __syncthreads();
    for (int off = 1; off < 256; off <<= 1) {
        int x = (t >= off) ? sc[t - off] : 0;
        __syncthreads();
        sc[t] += x;
        __syncthreads();
    }
    int excl = sc[t] - v;
    rp[b * 256 + t] = s0 + excl;
    nd[b * 256 + t] = rsqrtf((float)max(v, 1));
    cur[t] = excl;
    __syncthreads();
    for (int i = t; i < n; i += 256) {
        uint rc = recs[i];
        int p = atomicAdd(&cur[rc & 255u], 1);        // LDS atomic
        colst[p] = (int)(rc >> 8);
    }
    __syncthreads();
    for (int i = t; i < n; i += 256) col[s0 + i] = colst[i];
    if (b == 0) {
        if (t == 0) rp[NN] = NE;
        if (t < 64) col[NE + t] = 0;   // zero overshoot pad (safe gather target)
    }
}

// K5: one block per src-bucket: LDS histogram -> ns (rsqrt deg_out)
__global__ __launch_bounds__(256) void k_shist(
        const ushort* __restrict__ srec, const int* __restrict__ bbs,
        float* __restrict__ ns) {
    __shared__ int hist[256];
    int t = threadIdx.x, b = blockIdx.x;
    hist[t] = 0;
    __syncthreads();
    int s0 = bbs[b], e0 = bbs[b + 1];
    for (int i = s0 + t; i < e0; i += 256)
        atomicAdd(&hist[srec[i] & 255], 1);
    __syncthreads();
    ns[b * 256 + t] = rsqrtf((float)max(hist[t], 1));
}

// xs(bf16) = hx * norm_src; one dword (2 elems) per thread
__global__ void k_scale(const float* __restrict__ hx, const float* __restrict__ ns,
                        uint* __restrict__ xs) {
    int i = blockIdx.x * blockDim.x + threadIdx.x;  // over NN*64 dwords
    float2 v = ((const float2*)hx)[i];
    float s = ns[i >> 6];
    xs[i] = (uint)f2b(v.x * s) | ((uint)f2b(v.y * s) << 16);
}

// W (fp32 [k][n]) -> Wt (bf16 [n][k])
__global__ void k_wconv(const float* __restrict__ W, ushort* __restrict__ Wt) {
    int t = blockIdx.x * blockDim.x + threadIdx.x;  // 16384
    int n = t >> 7, k = t & 127;
    Wt[n * 128 + k] = f2b(W[k * 128 + n]);
}

// ---------------------------------------------------------------------------
// Fused conv layer — coalesced cooperative gather (R6) + R8 fix: remove
// scalar-load serialization from the address chain.
//   - col values prefetched ONE ITERATION AHEAD into a per-lane register
//     (cA covers next iter's 16 edges); extracted with readlane -> the
//     X-load address needs no memory op (was: dependent s_load ~100-200cy
//     x4 per iteration).
//   - all 17 rp row bounds preloaded once; FLUSHROWS uses dynamic readlane
//     (was: dependent s_load per row flush).
// ---------------------------------------------------------------------------
#define ISSUE4(x0, x1, x2, x3, CR, K) { \
    int c0_ = __builtin_amdgcn_readlane((int)(CR), (K)); \
    int c1_ = __builtin_amdgcn_readlane((int)(CR), (K) + 1); \
    int c2_ = __builtin_amdgcn_readlane((int)(CR), (K) + 2); \
    int c3_ = __builtin_amdgcn_readlane((int)(CR), (K) + 3); \
    x0 = X32[(size_t)c0_ * 64 + lane]; \
    x1 = X32[(size_t)c1_ * 64 + lane]; \
    x2 = X32[(size_t)c2_ * 64 + lane]; \
    x3 = X32[(size_t)c3_ * 64 + lane]; }

#define FLUSHROWS(J) \
    while ((J) >= next_e && r < 15) { \
        *(float2*)&Af[r * 132 + 2 * lane] = make_float2(a0, a1); \
        a0 = 0.f; a1 = 0.f; r++; \
        next_e = __builtin_amdgcn_readlane(rpv, r + 1); }

#define PROC1(xv, J) { FLUSHROWS(J) \
    if ((J) < E) { a0 += bl(xv); a1 += bh(xv); } }

__global__ __launch_bounds__(64, 2) void k_fused(
        const uint* __restrict__ X32,     // xs as dwords: node*64 + lane
        const int* __restrict__ rp, const int* __restrict__ col,
        const float* __restrict__ nd, const float* __restrict__ ns,
        const uint4* __restrict__ Wg,     // Wt bf16 [n][k] as uint4: n*16+chunk
        const float* __restrict__ b, int do_scale,
        ushort* __restrict__ out) {
    __shared__ float Af[16 * 132];        // 8.25 KB; +4 dword row pad (banks)
    int lane = threadIdx.x;
    int rr = lane & 15;     // fragment row / C col
    int q = lane >> 4;      // fragment k-quad / C row-quad
    int nb = blockIdx.x * 16;

    // all row bounds in registers: rpv lane i holds rp[nb+i] (i<=16)
    int rpv = rp[nb + (lane < 16 ? lane : 16)];
    int S = __builtin_amdgcn_readlane(rpv, 0);
    int E = __builtin_amdgcn_readlane(rpv, 16);
    int r = 0;
    int next_e = __builtin_amdgcn_readlane(rpv, 1);
    float a0 = 0.f, a1 = 0.f;

    // col prefetch registers: lanes 0..15 hold 16 consecutive col values
    int c0 = col[S + rr];          // covers [S, S+16)  (needed now)
    int cA = col[S + 16 + rr];     // covers [S+16, S+32) (arrives during prologue)

    uint xa0, xa1, xa2, xa3, xb0, xb1, xb2, xb3;
    uint xc0, xc1, xc2, xc3, xd0, xd1, xd2, xd3;
    int j = S;
    ISSUE4(xa0, xa1, xa2, xa3, c0, 0)
    ISSUE4(xb0, xb1, xb2, xb3, c0, 4)
    ISSUE4(xc0, xc1, xc2, xc3, c0, 8)
    ISSUE4(xd0, xd1, xd2, xd3, c0, 12)
    for (; j + 16 <= E; j += 16) {
        int cF = col[j + 32 + rr];          // prefetch next iter's cols
        PROC1(xa0, j)      PROC1(xa1, j + 1)  PROC1(xa2, j + 2)  PROC1(xa3, j + 3)
        ISSUE4(xa0, xa1, xa2, xa3, cA, 0)
        PROC1(xb0, j + 4)  PROC1(xb1, j + 5)  PROC1(xb2, j + 6)  PROC1(xb3, j + 7)
        ISSUE4(xb0, xb1, xb2, xb3, cA, 4)
        PROC1(xc0, j + 8)  PROC1(xc1, j + 9)  PROC1(xc2, j + 10) PROC1(xc3, j + 11)
        ISSUE4(xc0, xc1, xc2, xc3, cA, 8)
        PROC1(xd0, j + 12) PROC1(xd1, j + 13) PROC1(xd2, j + 14) PROC1(xd3, j + 15)
        ISSUE4(xd0, xd1, xd2, xd3, cA, 12)
        cA = cF;
    }
    PROC1(xa0, j)      PROC1(xa1, j + 1)  PROC1(xa2, j + 2)  PROC1(xa3, j + 3)
    PROC1(xb0, j + 4)  PROC1(xb1, j + 5)  PROC1(xb2, j + 6)  PROC1(xb3, j + 7)
    PROC1(xc0, j + 8)  PROC1(xc1, j + 9)  PROC1(xc2, j + 10) PROC1(xc3, j + 11)
    PROC1(xd0, j + 12) PROC1(xd1, j + 13) PROC1(xd2, j + 14) PROC1(xd3, j + 15)
    for (; r < 16; r++) {
        *(float2*)&Af[r * 132 + 2 * lane] = make_float2(a0, a1);
        a0 = 0.f; a1 = 0.f;
    }

    // A-fragments from LDS (scale by norm_dst), then MFMA
    float ndv = nd[nb + rr];
    bf16x8 afr[4];
    #pragma unroll
    for (int ks = 0; ks < 4; ks++) {
        const f32x4* Afv = (const f32x4*)&Af[rr * 132 + ks * 32 + q * 8];
        f32x4 v0 = Afv[0], v1 = Afv[1];
        union { u16x8 u; bf16x8 f; } cv;
        cv.u[0] = f2b(v0[0] * ndv); cv.u[1] = f2b(v0[1] * ndv);
        cv.u[2] = f2b(v0[2] * ndv); cv.u[3] = f2b(v0[3] * ndv);
        cv.u[4] = f2b(v1[0] * ndv); cv.u[5] = f2b(v1[1] * ndv);
        cv.u[6] = f2b(v1[2] * ndv); cv.u[7] = f2b(v1[3] * ndv);
        afr[ks] = cv.f;
    }

    f32x4 cacc[8] = {};
    #pragma unroll
    for (int ks = 0; ks < 4; ks++) {
        #pragma unroll
        for (int ni = 0; ni < 8; ni++) {
            union { uint4 u; bf16x8 f; } bw;
            bw.u = Wg[(size_t)(ni * 16 + rr) * 16 + ks * 4 + q];
            cacc[ni] = __builtin_amdgcn_mfma_f32_16x16x32_bf16(
                afr[ks], bw.f, cacc[ni], 0, 0, 0);
        }
    }

    // epilogue: bias + relu + (ns fold) -> bf16, staged in LDS (reuse Af)
    ushort* Cs = (ushort*)Af;             // [16][128]
    float sc4[4];
    #pragma unroll
    for (int rg = 0; rg < 4; rg++)
        sc4[rg] = do_scale ? ns[nb + q * 4 + rg] : 1.f;
    #pragma unroll
    for (int ni = 0; ni < 8; ni++) {
        int c = ni * 16 + rr;
        float bb = b[c];
        #pragma unroll
        for (int rg = 0; rg < 4; rg++) {
            float v = fmaxf(cacc[ni][rg] + bb, 0.f) * sc4[rg];
            Cs[(q * 4 + rg) * 128 + c] = f2b(v);
        }
    }
    const uint4* Cs4 = (const uint4*)Cs;
    uint4* Og = (uint4*)(out + (size_t)nb * 128);
    #pragma unroll
    for (int it = 0; it < 4; it++)
        Og[it * 64 + lane] = Cs4[it * 64 + lane];
}

// graph row pointers via binary search on sorted graph_id
__global__ void k_gptr(const int* __restrict__ gid, int* __restrict__ gptr) {
    int g = blockIdx.x * blockDim.x + threadIdx.x;
    if (g <= NG) {
        int lo = 0, hi = NN;
        while (lo < hi) {
            int mid = (lo + hi) >> 1;
            if (gid[mid] < g) lo = mid + 1; else hi = mid;
        }
        gptr[g] = lo;
    }
}

// mean-pool: block per graph, 256 threads, dword loads, 4-way row parallel
__global__ __launch_bounds__(256) void k_pool(
        const uint* __restrict__ h, const int* __restrict__ gptr,
        float* __restrict__ pooled) {
    __shared__ float2 part[256];
    int g = blockIdx.x, t = threadIdx.x;
    int d = t & 63, qq = t >> 6;
    int s = gptr[g], e = gptr[g + 1];
    float2 acc = make_float2(0.f, 0.f);
    for (int i = s + qq; i < e; i += 4) {
        uint x = h[(size_t)i * 64 + d];
        acc.x += bl(x); acc.y += bh(x);
    }
    part[t] = acc;
    __syncthreads();
    if (t < 64) {
        float2 p0 = part[t], p1 = part[t + 64], p2 = part[t + 128], p3 = part[t + 192];
        float inv = 1.f / fmaxf((float)(e - s), 1.f);
        ((float2*)(pooled + g * 128))[t] =
            make_float2((p0.x + p1.x + p2.x + p3.x) * inv,
                        (p0.y + p1.y + p2.y + p3.y) * inv);
    }
}

__global__ __launch_bounds__(64) void k_head(
        const float* __restrict__ pooled,
        const float* __restrict__ Wp1, const float* __restrict__ bp1,
        const float* __restrict__ Wp2, const float* __restrict__ bp2,
        float* __restrict__ scores) {
    __shared__ float p[128];
    __shared__ float t1[64];
    int g = blockIdx.x, t = threadIdx.x;
    p[t] = pooled[g * 128 + t];
    p[t + 64] = pooled[g * 128 + 64 + t];
    __syncthreads();
    float a = 0.f;
    for (int k = 0; k < 128; k++) a += p[k] * Wp1[k * 64 + t];
    t1[t] = fmaxf(a + bp1[t], 0.f);
    __syncthreads();
    if (t < NCLS) {
        float s = bp2[t];
        for (int k = 0; k < 64; k++) s += t1[k] * Wp2[k * NCLS + t];
        scores[g * NCLS + t] = s;
    }
}

extern "C" void kernel_launch(void* const* d_in, const int* in_sizes, int n_in,
                              void* d_out, int out_size, void* d_ws, size_t ws_size,
                              hipStream_t stream) {
    const float* hx  = (const float*)d_in[0];
    const int*   src = (const int*)d_in[1];
    const int*   dst = (const int*)d_in[2];
    const int*   gid = (const int*)d_in[3];
    const float* Ws[6], *bs[6];
    for (int l = 0; l < 6; l++) {
        Ws[l] = (const float*)d_in[5 + 2 * l];
        bs[l] = (const float*)d_in[6 + 2 * l];
    }
    const float* Wp1 = (const float*)d_in[17];
    const float* bp1 = (const float*)d_in[18];
    const float* Wp2 = (const float*)d_in[19];
    const float* bp2 = (const float*)d_in[20];
    float* scores = (float*)d_out;

    // ---- workspace layout (16B-aligned chunks) ----
    char* w = (char*)d_ws;
    ushort* xsA = (ushort*)w;     w += (size_t)NN * DF * 2;        // 16 MB
    ushort* xsB = (ushort*)w;     w += (size_t)NN * DF * 2;        // 16 MB
    ushort* Wt = (ushort*)w;      w += (size_t)6 * 128 * 128 * 2;  // 192 KB
    int* Md   = (int*)w;          w += 256 * 256 * 4;              // 256 KB
    int* Ms   = (int*)w;          w += 256 * 256 * 4;
    int* Bd   = (int*)w;          w += 256 * 256 * 4;
    int* Bs   = (int*)w;          w += 256 * 256 * 4;
    int* bbd  = (int*)w;          w += 257 * 4 + 12;
    int* bbs  = (int*)w;          w += 257 * 4 + 12;
    int* rp   = (int*)w;          w += (NN + 1) * 4 + 12;
    int* colv = (int*)w;          w += (NE + 64) * 4;              // +64 pad
    float* ns   = (float*)w;      w += NN * 4;
    float* ndst = (float*)w;      w += NN * 4;
    int* gptr   = (int*)w;        w += (NG + 1) * 4 + 12;
    float* pooled = (float*)w;    w += NG * DF * 4;
    // bucket records alias the head of xsB (dead until k_fused layer 0,
    // which launches after k_bsort/k_shist consumed them — stream-ordered)
    uint*   drec = (uint*)xsB;                          // 2 MB
    ushort* srec = (ushort*)((char*)xsB + (size_t)NE * 4);  // 1 MB

    k_hist<<<NBLK, 256, 0, stream>>>(src, dst, Md, Ms);
    k_colscan<<<2, 256, 0, stream>>>(Md, Ms, Bd, Bs, bbd, bbs);
    k_place<<<NBLK, 256, 0, stream>>>(src, dst, Bd, bbd, Bs, bbs, drec, srec);
    k_bsort<<<NBLK, 256, 0, stream>>>(drec, bbd, colv, rp, ndst);
    k_shist<<<NBLK, 256, 0, stream>>>(srec, bbs, ns);
    k_scale<<<NN * 64 / 256, 256, 0, stream>>>(hx, ns, (uint*)xsA);
    for (int l = 0; l < 6; l++)
        k_wconv<<<64, 256, 0, stream>>>(Ws[l], Wt + (size_t)l * 128 * 128);

    ushort* cur = xsA;
    ushort* nxt = xsB;
    for (int l = 0; l < 6; l++) {
        k_fused<<<NN / 16, 64, 0, stream>>>(
            (const uint*)cur, rp, colv, ndst, ns,
            (const uint4*)(Wt + (size_t)l * 128 * 128), bs[l],
            (l < 5) ? 1 : 0, nxt);
        ushort* tmp = cur; cur = nxt; nxt = tmp;
    }

    k_gptr<<<3, 256, 0, stream>>>(gid, gptr);
    k_pool<<<NG, 256, 0, stream>>>((const uint*)cur, gptr, pooled);
    k_head<<<NG, 64, 0, stream>>>(pooled, Wp1, bp1, Wp2, bp2, scores);
}

// Round 10
// 264.502 us; speedup vs baseline: 1.8127x; 1.0808x over previous
//
#include <hip/hip_runtime.h>
#include <hip/hip_bf16.h>

#define NN 65536
#define NE 524288
#define DF 128
#define NG 512
#define NCLS 10
#define NBLK 256
#define EPB (NE / NBLK)    // 2048 edges per block
#define EPT (EPB / 256)    // 8 edges per thread

typedef __bf16 bf16x8 __attribute__((ext_vector_type(8)));
typedef float f32x4 __attribute__((ext_vector_type(4)));
typedef ushort u16x8 __attribute__((ext_vector_type(8)));

__device__ __forceinline__ float bl(uint x) { return __uint_as_float(x << 16); }
__device__ __forceinline__ float bh(uint x) { return __uint_as_float(x & 0xffff0000u); }
__device__ __forceinline__ ushort f2b(float f) {
    uint u = __float_as_uint(f);
    return (ushort)((u + 0x7fffu + ((u >> 16) & 1u)) >> 16);  // RN-even
}

// ---------------------------------------------------------------------------
// Atomic-free CSR build (R6: global atomics write ~64B/op through to HBM).
// 2-level bucket sort using only LDS atomics + precomputed placement bases.
// ---------------------------------------------------------------------------

// K1: per-block 256-bin histograms of dst>>8 and src>>8
__global__ __launch_bounds__(256) void k_hist(
        const int* __restrict__ src, const int* __restrict__ dst,
        int* __restrict__ Md, int* __restrict__ Ms) {
    __shared__ int hd[256], hs[256];
    int t = threadIdx.x, b = blockIdx.x;
    hd[t] = 0; hs[t] = 0;
    __syncthreads();
    int base = b * EPB;
    for (int k = 0; k < EPT; k++) {
        int e = base + k * 256 + t;
        atomicAdd(&hd[dst[e] >> 8], 1);
        atomicAdd(&hs[src[e] >> 8], 1);
    }
    __syncthreads();
    Md[b * 256 + t] = hd[t];
    Ms[b * 256 + t] = hs[t];
}

// K2 (2 blocks: blk0=dst, blk1=src): column scan -> per-(block,bin) bases +
// bucket bases
__global__ __launch_bounds__(256) void k_colscan(
        const int* __restrict__ Md, const int* __restrict__ Ms,
        int* __restrict__ Bd, int* __restrict__ Bs,
        int* __restrict__ bbd, int* __restrict__ bbs) {
    __shared__ int tot[256];
    int t = threadIdx.x;
    const int* M = blockIdx.x ? Ms : Md;
    int* B = blockIdx.x ? Bs : Bd;
    int* bb = blockIdx.x ? bbs : bbd;
    int run = 0;
    #pragma unroll 16
    for (int b = 0; b < NBLK; b++) { B[b * 256 + t] = run; run += M[b * 256 + t]; }
    tot[t] = run;
    __syncthreads();
    if (t == 0) { int r = 0; for (int i = 0; i < 256; i++) { int c = tot[i]; tot[i] = r; r += c; } }
    __syncthreads();
    bb[t] = tot[t];
    if (t == 0) bb[256] = NE;
}

// K3: atomic-free placement into buckets (LDS cursors seeded from bases)
__global__ __launch_bounds__(256) void k_place(
        const int* __restrict__ src, const int* __restrict__ dst,
        const int* __restrict__ Bd, const int* __restrict__ bbd,
        const int* __restrict__ Bs, const int* __restrict__ bbs,
        uint* __restrict__ drec, ushort* __restrict__ srec) {
    __shared__ int cd[256], cs[256];
    int t = threadIdx.x, b = blockIdx.x;
    cd[t] = bbd[t] + Bd[b * 256 + t];
    cs[t] = bbs[t] + Bs[b * 256 + t];
    __syncthreads();
    int base = b * EPB;
    for (int k = 0; k < EPT; k++) {
        int e = base + k * 256 + t;
        int d = dst[e], s = src[e];
        int pd = atomicAdd(&cd[d >> 8], 1);           // LDS atomic
        drec[pd] = ((uint)s << 8) | (uint)(d & 255);
        int ps = atomicAdd(&cs[s >> 8], 1);           // LDS atomic
        srec[ps] = (ushort)(s & 255);
    }
}

// K4+K5 merged (512 blocks): b<256 -> dst-bucket counting sort (col, rp, nd);
// b>=256 -> src-bucket histogram (ns). Independent, same dependency level.
__global__ __launch_bounds__(256) void k_bshist(
        const uint* __restrict__ drec, const int* __restrict__ bbd,
        const ushort* __restrict__ srec, const int* __restrict__ bbs,
        int* __restrict__ col, int* __restrict__ rp,
        float* __restrict__ nd, float* __restrict__ ns) {
    __shared__ int hist[256], cur[256], sc[256];
    __shared__ uint recs[4096];
    __shared__ int colst[4096];
    int t = threadIdx.x;
    if (blockIdx.x >= 256) {
        // ---- src-bucket histogram -> ns ----
        int b = blockIdx.x - 256;
        hist[t] = 0;
        __syncthreads();
        int s0 = bbs[b], e0 = bbs[b + 1];
        for (int i = s0 + t; i < e0; i += 256)
            atomicAdd(&hist[srec[i] & 255], 1);
        __syncthreads();
        ns[b * 256 + t] = rsqrtf((float)max(hist[t], 1));
        return;
    }
    // ---- dst-bucket counting sort ----
    int b = blockIdx.x;
    int s0 = bbd[b];
    int n = min(bbd[b + 1] - s0, 4096);
    hist[t] = 0;
    __syncthreads();
    for (int i = t; i < n; i += 256) {
        uint rc = drec[s0 + i];
        recs[i] = rc;
        atomicAdd(&hist[rc & 255u], 1);
    }
    __syncthreads();
    int v = hist[t];
    sc[t] = v;
    __syncthreads();
    for (int off = 1; off < 256; off <<= 1) {
        int x = (t >= off) ? sc[t - off] : 0;
        __syncthreads();
        sc[t] += x;
        __syncthreads();
    }
    int excl = sc[t] - v;
    rp[b * 256 + t] = s0 + excl;
    nd[b * 256 + t] = rsqrtf((float)max(v, 1));
    cur[t] = excl;
    __syncthreads();
    for (int i = t; i < n; i += 256) {
        uint rc = recs[i];
        int p = atomicAdd(&cur[rc & 255u], 1);        // LDS atomic
        colst[p] = (int)(rc >> 8);
    }
    __syncthreads();
    for (int i = t; i < n; i += 256) col[s0 + i] = colst[i];
    if (b == 0) {
        if (t == 0) rp[NN] = NE;
        if (t < 64) col[NE + t] = 0;   // zero overshoot pad (safe gather target)
    }
}

// K6 merged: blocks [0,8192) = xs scale (float4->uint2); blocks [8192,8576) =
// all 6 layers' W transpose+bf16 convert (6*16384 = 98304 elems = 384 blocks).
// R9 bug: launched only 96 wconv blocks -> Wt layers 1.5-5 held poison.
__global__ __launch_bounds__(256) void k_scale_wconv(
        const float* __restrict__ hx, const float* __restrict__ ns,
        uint2* __restrict__ xs2,
        const float* __restrict__ W0, const float* __restrict__ W1,
        const float* __restrict__ W2, const float* __restrict__ W3,
        const float* __restrict__ W4, const float* __restrict__ W5,
        ushort* __restrict__ Wt) {
    if (blockIdx.x < 8192) {
        int i = blockIdx.x * 256 + threadIdx.x;   // over NN*32 float4 groups
        float4 v = ((const float4*)hx)[i];
        float s = ns[i >> 5];
        uint2 o;
        o.x = (uint)f2b(v.x * s) | ((uint)f2b(v.y * s) << 16);
        o.y = (uint)f2b(v.z * s) | ((uint)f2b(v.w * s) << 16);
        xs2[i] = o;
    } else {
        int t = (blockIdx.x - 8192) * 256 + threadIdx.x;  // 0..98303
        int l = t >> 14, r = t & 16383;
        const float* W = l == 0 ? W0 : l == 1 ? W1 : l == 2 ? W2
                       : l == 3 ? W3 : l == 4 ? W4 : W5;
        int n = r >> 7, k = r & 127;
        Wt[l * 16384 + n * 128 + k] = f2b(W[k * 128 + n]);
    }
}

// ---------------------------------------------------------------------------
// Fused conv layer — FROZEN from R8 (coalesced cooperative gather + register
// col/rp prefetch). ~35 us/dispatch = 3.7 TB/s random-gather service =
// per-CU line-service cap (R3 more-waves null, R4 sort null).
// ---------------------------------------------------------------------------
#define ISSUE4(x0, x1, x2, x3, CR, K) { \
    int c0_ = __builtin_amdgcn_readlane((int)(CR), (K)); \
    int c1_ = __builtin_amdgcn_readlane((int)(CR), (K) + 1); \
    int c2_ = __builtin_amdgcn_readlane((int)(CR), (K) + 2); \
    int c3_ = __builtin_amdgcn_readlane((int)(CR), (K) + 3); \
    x0 = X32[(size_t)c0_ * 64 + lane]; \
    x1 = X32[(size_t)c1_ * 64 + lane]; \
    x2 = X32[(size_t)c2_ * 64 + lane]; \
    x3 = X32[(size_t)c3_ * 64 + lane]; }

#define FLUSHROWS(J) \
    while ((J) >= next_e && r < 15) { \
        *(float2*)&Af[r * 132 + 2 * lane] = make_float2(a0, a1); \
        a0 = 0.f; a1 = 0.f; r++; \
        next_e = __builtin_amdgcn_readlane(rpv, r + 1); }

#define PROC1(xv, J) { FLUSHROWS(J) \
    if ((J) < E) { a0 += bl(xv); a1 += bh(xv); } }

__global__ __launch_bounds__(64, 2) void k_fused(
        const uint* __restrict__ X32,     // xs as dwords: node*64 + lane
        const int* __restrict__ rp, const int* __restrict__ col,
        const float* __restrict__ nd, const float* __restrict__ ns,
        const uint4* __restrict__ Wg,     // Wt bf16 [n][k] as uint4: n*16+chunk
        const float* __restrict__ b, int do_scale,
        ushort* __restrict__ out) {
    __shared__ float Af[16 * 132];        // 8.25 KB; +4 dword row pad (banks)
    int lane = threadIdx.x;
    int rr = lane & 15;     // fragment row / C col
    int q = lane >> 4;      // fragment k-quad / C row-quad
    int nb = blockIdx.x * 16;

    // all row bounds in registers: rpv lane i holds rp[nb+i] (i<=16)
    int rpv = rp[nb + (lane < 16 ? lane : 16)];
    int S = __builtin_amdgcn_readlane(rpv, 0);
    int E = __builtin_amdgcn_readlane(rpv, 16);
    int r = 0;
    int next_e = __builtin_amdgcn_readlane(rpv, 1);
    float a0 = 0.f, a1 = 0.f;

    // col prefetch registers: lanes 0..15 hold 16 consecutive col values
    int c0 = col[S + rr];          // covers [S, S+16)
    int cA = col[S + 16 + rr];     // covers [S+16, S+32)

    uint xa0, xa1, xa2, xa3, xb0, xb1, xb2, xb3;
    uint xc0, xc1, xc2, xc3, xd0, xd1, xd2, xd3;
    int j = S;
    ISSUE4(xa0, xa1, xa2, xa3, c0, 0)
    ISSUE4(xb0, xb1, xb2, xb3, c0, 4)
    ISSUE4(xc0, xc1, xc2, xc3, c0, 8)
    ISSUE4(xd0, xd1, xd2, xd3, c0, 12)
    for (; j + 16 <= E; j += 16) {
        int cF = col[j + 32 + rr];          // prefetch next iter's cols
        PROC1(xa0, j)      PROC1(xa1, j + 1)  PROC1(xa2, j + 2)  PROC1(xa3, j + 3)
        ISSUE4(xa0, xa1, xa2, xa3, cA, 0)
        PROC1(xb0, j + 4)  PROC1(xb1, j + 5)  PROC1(xb2, j + 6)  PROC1(xb3, j + 7)
        ISSUE4(xb0, xb1, xb2, xb3, cA, 4)
        PROC1(xc0, j + 8)  PROC1(xc1, j + 9)  PROC1(xc2, j + 10) PROC1(xc3, j + 11)
        ISSUE4(xc0, xc1, xc2, xc3, cA, 8)
        PROC1(xd0, j + 12) PROC1(xd1, j + 13) PROC1(xd2, j + 14) PROC1(xd3, j + 15)
        ISSUE4(xd0, xd1, xd2, xd3, cA, 12)
        cA = cF;
    }
    PROC1(xa0, j)      PROC1(xa1, j + 1)  PROC1(xa2, j + 2)  PROC1(xa3, j + 3)
    PROC1(xb0, j + 4)  PROC1(xb1, j + 5)  PROC1(xb2, j + 6)  PROC1(xb3, j + 7)
    PROC1(xc0, j + 8)  PROC1(xc1, j + 9)  PROC1(xc2, j + 10) PROC1(xc3, j + 11)
    PROC1(xd0, j + 12) PROC1(xd1, j + 13) PROC1(xd2, j + 14) PROC1(xd3, j + 15)
    for (; r < 16; r++) {
        *(float2*)&Af[r * 132 + 2 * lane] = make_float2(a0, a1);
        a0 = 0.f; a1 = 0.f;
    }

    // A-fragments from LDS (scale by norm_dst), then MFMA
    float ndv = nd[nb + rr];
    bf16x8 afr[4];
    #pragma unroll
    for (int ks = 0; ks < 4; ks++) {
        const f32x4* Afv = (const f32x4*)&Af[rr * 132 + ks * 32 + q * 8];
        f32x4 v0 = Afv[0], v1 = Afv[1];
        union { u16x8 u; bf16x8 f; } cv;
        cv.u[0] = f2b(v0[0] * ndv); cv.u[1] = f2b(v0[1] * ndv);
        cv.u[2] = f2b(v0[2] * ndv); cv.u[3] = f2b(v0[3] * ndv);
        cv.u[4] = f2b(v1[0] * ndv); cv.u[5] = f2b(v1[1] * ndv);
        cv.u[6] = f2b(v1[2] * ndv); cv.u[7] = f2b(v1[3] * ndv);
        afr[ks] = cv.f;
    }

    f32x4 cacc[8] = {};
    #pragma unroll
    for (int ks = 0; ks < 4; ks++) {
        #pragma unroll
        for (int ni = 0; ni < 8; ni++) {
            union { uint4 u; bf16x8 f; } bw;
            bw.u = Wg[(size_t)(ni * 16 + rr) * 16 + ks * 4 + q];
            cacc[ni] = __builtin_amdgcn_mfma_f32_16x16x32_bf16(
                afr[ks], bw.f, cacc[ni], 0, 0, 0);
        }
    }

    // epilogue: bias + relu + (ns fold) -> bf16, staged in LDS (reuse Af)
    ushort* Cs = (ushort*)Af;             // [16][128]
    float sc4[4];
    #pragma unroll
    for (int rg = 0; rg < 4; rg++)
        sc4[rg] = do_scale ? ns[nb + q * 4 + rg] : 1.f;
    #pragma unroll
    for (int ni = 0; ni < 8; ni++) {
        int c = ni * 16 + rr;
        float bb = b[c];
        #pragma unroll
        for (int rg = 0; rg < 4; rg++) {
            float v = fmaxf(cacc[ni][rg] + bb, 0.f) * sc4[rg];
            Cs[(q * 4 + rg) * 128 + c] = f2b(v);
        }
    }
    const uint4* Cs4 = (const uint4*)Cs;
    uint4* Og = (uint4*)(out + (size_t)nb * 128);
    #pragma unroll
    for (int it = 0; it < 4; it++)
        Og[it * 64 + lane] = Cs4[it * 64 + lane];
}

// mean-pool with inlined graph-range binary search; uint2 loads, 8-way row par
__global__ __launch_bounds__(256) void k_pool(
        const uint2* __restrict__ h2, const int* __restrict__ gid,
        float* __restrict__ pooled) {
    __shared__ int se[2];
    __shared__ float4 part[256];
    int g = blockIdx.x, t = threadIdx.x;
    if (t < 2) {
        int tgt = g + t;
        int lo = 0, hi = NN;
        while (lo < hi) { int mid = (lo + hi) >> 1; if (gid[mid] < tgt) lo = mid + 1; else hi = mid; }
        se[t] = lo;
    }
    __syncthreads();
    int s = se[0], e = se[1];
    int d2 = t & 31, qq = t >> 5;
    float4 acc = make_float4(0.f, 0.f, 0.f, 0.f);
    for (int i = s + qq; i < e; i += 8) {
        uint2 x = h2[(size_t)i * 32 + d2];
        acc.x += bl(x.x); acc.y += bh(x.x);
        acc.z += bl(x.y); acc.w += bh(x.y);
    }
    part[t] = acc;
    __syncthreads();
    if (t < 32) {
        float4 a = part[t];
        #pragma unroll
        for (int k = 1; k < 8; k++) {
            float4 p = part[t + 32 * k];
            a.x += p.x; a.y += p.y; a.z += p.z; a.w += p.w;
        }
        float inv = 1.f / fmaxf((float)(e - s), 1.f);
        ((float4*)(pooled + g * 128))[t] =
            make_float4(a.x * inv, a.y * inv, a.z * inv, a.w * inv);
    }
}

__global__ __launch_bounds__(64) void k_head(
        const float* __restrict__ pooled,
        const float* __restrict__ Wp1, const float* __restrict__ bp1,
        const float* __restrict__ Wp2, const float* __restrict__ bp2,
        float* __restrict__ scores) {
    __shared__ float p[128];
    __shared__ float t1[64];
    int g = blockIdx.x, t = threadIdx.x;
    p[t] = pooled[g * 128 + t];
    p[t + 64] = pooled[g * 128 + 64 + t];
    __syncthreads();
    float a = 0.f;
    for (int k = 0; k < 128; k++) a += p[k] * Wp1[k * 64 + t];
    t1[t] = fmaxf(a + bp1[t], 0.f);
    __syncthreads();
    if (t < NCLS) {
        float s = bp2[t];
        for (int k = 0; k < 64; k++) s += t1[k] * Wp2[k * NCLS + t];
        scores[g * NCLS + t] = s;
    }
}

extern "C" void kernel_launch(void* const* d_in, const int* in_sizes, int n_in,
                              void* d_out, int out_size, void* d_ws, size_t ws_size,
                              hipStream_t stream) {
    const float* hx  = (const float*)d_in[0];
    const int*   src = (const int*)d_in[1];
    const int*   dst = (const int*)d_in[2];
    const int*   gid = (const int*)d_in[3];
    const float* Ws[6], *bs[6];
    for (int l = 0; l < 6; l++) {
        Ws[l] = (const float*)d_in[5 + 2 * l];
        bs[l] = (const float*)d_in[6 + 2 * l];
    }
    const float* Wp1 = (const float*)d_in[17];
    const float* bp1 = (const float*)d_in[18];
    const float* Wp2 = (const float*)d_in[19];
    const float* bp2 = (const float*)d_in[20];
    float* scores = (float*)d_out;

    // ---- workspace layout (16B-aligned chunks) ----
    char* w = (char*)d_ws;
    ushort* xsA = (ushort*)w;     w += (size_t)NN * DF * 2;        // 16 MB
    ushort* xsB = (ushort*)w;     w += (size_t)NN * DF * 2;        // 16 MB
    ushort* Wt = (ushort*)w;      w += (size_t)6 * 128 * 128 * 2;  // 192 KB
    int* Md   = (int*)w;          w += 256 * 256 * 4;              // 256 KB
    int* Ms   = (int*)w;          w += 256 * 256 * 4;
    int* Bd   = (int*)w;          w += 256 * 256 * 4;
    int* Bs   = (int*)w;          w += 256 * 256 * 4;
    int* bbd  = (int*)w;          w += 257 * 4 + 12;
    int* bbs  = (int*)w;          w += 257 * 4 + 12;
    int* rp   = (int*)w;          w += (NN + 1) * 4 + 12;
    int* colv = (int*)w;          w += (NE + 64) * 4;              // +64 pad
    float* ns   = (float*)w;      w += NN * 4;
    float* ndst = (float*)w;      w += NN * 4;
    float* pooled = (float*)w;    w += NG * DF * 4;
    // bucket records alias the head of xsB (dead until k_fused layer 0,
    // which launches after k_bshist consumed them — stream-ordered)
    uint*   drec = (uint*)xsB;                          // 2 MB
    ushort* srec = (ushort*)((char*)xsB + (size_t)NE * 4);  // 1 MB

    k_hist<<<NBLK, 256, 0, stream>>>(src, dst, Md, Ms);
    k_colscan<<<2, 256, 0, stream>>>(Md, Ms, Bd, Bs, bbd, bbs);
    k_place<<<NBLK, 256, 0, stream>>>(src, dst, Bd, bbd, Bs, bbs, drec, srec);
    k_bshist<<<512, 256, 0, stream>>>(drec, bbd, srec, bbs, colv, rp, ndst, ns);
    k_scale_wconv<<<8192 + 384, 256, 0, stream>>>(
        hx, ns, (uint2*)xsA, Ws[0], Ws[1], Ws[2], Ws[3], Ws[4], Ws[5], Wt);

    ushort* cur = xsA;
    ushort* nxt = xsB;
    for (int l = 0; l < 6; l++) {
        k_fused<<<NN / 16, 64, 0, stream>>>(
            (const uint*)cur, rp, colv, ndst, ns,
            (const uint4*)(Wt + (size_t)l * 128 * 128), bs[l],
            (l < 5) ? 1 : 0, nxt);
        ushort* tmp = cur; cur = nxt; nxt = tmp;
    }

    k_pool<<<NG, 256, 0, stream>>>((const uint2*)cur, gid, pooled);
    k_head<<<NG, 64, 0, stream>>>(pooled, Wp1, bp1, Wp2, bp2, scores);
}

// Round 11
// 261.505 us; speedup vs baseline: 1.8335x; 1.0115x over previous
//
#include <hip/hip_runtime.h>
#include <hip/hip_bf16.h>

#define NN 65536
#define NE 524288
#define DF 128
#define NG 512
#define NCLS 10
#define NBLK 256
#define EPB (NE / NBLK)    // 2048 edges per block
#define EPT (EPB / 256)    // 8 edges per thread

typedef __bf16 bf16x8 __attribute__((ext_vector_type(8)));
typedef float f32x4 __attribute__((ext_vector_type(4)));
typedef ushort u16x8 __attribute__((ext_vector_type(8)));

__device__ __forceinline__ float bl(uint x) { return __uint_as_float(x << 16); }
__device__ __forceinline__ float bh(uint x) { return __uint_as_float(x & 0xffff0000u); }
__device__ __forceinline__ ushort f2b(float f) {
    uint u = __float_as_uint(f);
    return (ushort)((u + 0x7fffu + ((u >> 16) & 1u)) >> 16);  // RN-even
}

// ---------------------------------------------------------------------------
// Atomic-free CSR build (R6: global atomics write ~64B/op through to HBM).
// 2-level bucket sort using only LDS atomics + precomputed placement bases.
// ---------------------------------------------------------------------------

// K1: per-block 256-bin histograms of dst>>8 and src>>8
__global__ __launch_bounds__(256) void k_hist(
        const int* __restrict__ src, const int* __restrict__ dst,
        int* __restrict__ Md, int* __restrict__ Ms) {
    __shared__ int hd[256], hs[256];
    int t = threadIdx.x, b = blockIdx.x;
    hd[t] = 0; hs[t] = 0;
    __syncthreads();
    int base = b * EPB;
    for (int k = 0; k < EPT; k++) {
        int e = base + k * 256 + t;
        atomicAdd(&hd[dst[e] >> 8], 1);
        atomicAdd(&hs[src[e] >> 8], 1);
    }
    __syncthreads();
    Md[b * 256 + t] = hd[t];
    Ms[b * 256 + t] = hs[t];
}

// K2 (2 blocks: blk0=dst, blk1=src): column scan -> per-(block,bin) bases +
// bucket bases
__global__ __launch_bounds__(256) void k_colscan(
        const int* __restrict__ Md, const int* __restrict__ Ms,
        int* __restrict__ Bd, int* __restrict__ Bs,
        int* __restrict__ bbd, int* __restrict__ bbs) {
    __shared__ int tot[256];
    int t = threadIdx.x;
    const int* M = blockIdx.x ? Ms : Md;
    int* B = blockIdx.x ? Bs : Bd;
    int* bb = blockIdx.x ? bbs : bbd;
    int run = 0;
    #pragma unroll 16
    for (int b = 0; b < NBLK; b++) { B[b * 256 + t] = run; run += M[b * 256 + t]; }
    tot[t] = run;
    __syncthreads();
    if (t == 0) { int r = 0; for (int i = 0; i < 256; i++) { int c = tot[i]; tot[i] = r; r += c; } }
    __syncthreads();
    bb[t] = tot[t];
    if (t == 0) bb[256] = NE;
}

// K3: placement into buckets, LDS-STAGED (R11): per-block counting sort in
// LDS, then bin-ordered copy-out so consecutive threads write consecutive
// slots of the same bin (runs ~8 records) instead of 64 random 4B singles
// per wave (was ~1 line-touch per record + cross-XCD bucket-line ping-pong).
__global__ __launch_bounds__(256) void k_place(
        const int* __restrict__ src, const int* __restrict__ dst,
        const int* __restrict__ Bd, const int* __restrict__ bbd,
        const int* __restrict__ Bs, const int* __restrict__ bbs,
        uint* __restrict__ drec, ushort* __restrict__ srec) {
    __shared__ int cnt[256], scn[256];
    __shared__ uint stage[EPB];           // 8 KB
    __shared__ uchar sbin[EPB];           // 2 KB
    int t = threadIdx.x, b = blockIdx.x;
    int base = b * EPB;
    int dv[EPT], sv[EPT], rk[EPT];
    #pragma unroll
    for (int k = 0; k < EPT; k++) {
        int e = base + k * 256 + t;
        dv[k] = dst[e]; sv[k] = src[e];
    }

    // ---- dst pass: count, scan, stage, copy-out ----
    cnt[t] = 0;
    __syncthreads();
    #pragma unroll
    for (int k = 0; k < EPT; k++) rk[k] = atomicAdd(&cnt[dv[k] >> 8], 1);
    __syncthreads();
    int v = cnt[t];
    scn[t] = v;
    __syncthreads();
    for (int off = 1; off < 256; off <<= 1) {
        int x = (t >= off) ? scn[t - off] : 0;
        __syncthreads();
        scn[t] += x;
        __syncthreads();
    }
    #pragma unroll
    for (int k = 0; k < EPT; k++) {
        int bin = dv[k] >> 8;
        int slot = (scn[bin] - cnt[bin]) + rk[k];
        stage[slot] = ((uint)sv[k] << 8) | (uint)(dv[k] & 255);
        sbin[slot] = (uchar)bin;
    }
    __syncthreads();
    #pragma unroll
    for (int k = 0; k < EPT; k++) {
        int i = k * 256 + t;
        int bin = sbin[i];
        int local = i - (scn[bin] - cnt[bin]);
        drec[bbd[bin] + Bd[b * 256 + bin] + local] = stage[i];
    }
    __syncthreads();

    // ---- src pass: count, scan, stage (low byte), copy-out ----
    cnt[t] = 0;
    __syncthreads();
    #pragma unroll
    for (int k = 0; k < EPT; k++) rk[k] = atomicAdd(&cnt[sv[k] >> 8], 1);
    __syncthreads();
    v = cnt[t];
    scn[t] = v;
    __syncthreads();
    for (int off = 1; off < 256; off <<= 1) {
        int x = (t >= off) ? scn[t - off] : 0;
        __syncthreads();
        scn[t] += x;
        __syncthreads();
    }
    #pragma unroll
    for (int k = 0; k < EPT; k++) {
        int bin = sv[k] >> 8;
        int slot = (scn[bin] - cnt[bin]) + rk[k];
        stage[slot] = (uint)(sv[k] & 255);
        sbin[slot] = (uchar)bin;
    }
    __syncthreads();
    #pragma unroll
    for (int k = 0; k < EPT; k++) {
        int i = k * 256 + t;
        int bin = sbin[i];
        int local = i - (scn[bin] - cnt[bin]);
        srec[bbs[bin] + Bs[b * 256 + bin] + local] = (ushort)stage[i];
    }
}

// K4+K5 merged (512 blocks): b<256 -> dst-bucket counting sort (col, rp, nd);
// b>=256 -> src-bucket histogram (ns). Independent, same dependency level.
__global__ __launch_bounds__(256) void k_bshist(
        const uint* __restrict__ drec, const int* __restrict__ bbd,
        const ushort* __restrict__ srec, const int* __restrict__ bbs,
        int* __restrict__ col, int* __restrict__ rp,
        float* __restrict__ nd, float* __restrict__ ns) {
    __shared__ int hist[256], cur[256], sc[256];
    __shared__ uint recs[4096];
    __shared__ int colst[4096];
    int t = threadIdx.x;
    if (blockIdx.x >= 256) {
        // ---- src-bucket histogram -> ns ----
        int b = blockIdx.x - 256;
        hist[t] = 0;
        __syncthreads();
        int s0 = bbs[b], e0 = bbs[b + 1];
        for (int i = s0 + t; i < e0; i += 256)
            atomicAdd(&hist[srec[i] & 255], 1);
        __syncthreads();
        ns[b * 256 + t] = rsqrtf((float)max(hist[t], 1));
        return;
    }
    // ---- dst-bucket counting sort ----
    int b = blockIdx.x;
    int s0 = bbd[b];
    int n = min(bbd[b + 1] - s0, 4096);
    hist[t] = 0;
    __syncthreads();
    for (int i = t; i < n; i += 256) {
        uint rc = drec[s0 + i];
        recs[i] = rc;
        atomicAdd(&hist[rc & 255u], 1);
    }
    __syncthreads();
    int v = hist[t];
    sc[t] = v;
    __syncthreads();
    for (int off = 1; off < 256; off <<= 1) {
        int x = (t >= off) ? sc[t - off] : 0;
        __syncthreads();
        sc[t] += x;
        __syncthreads();
    }
    int excl = sc[t] - v;
    rp[b * 256 + t] = s0 + excl;
    nd[b * 256 + t] = rsqrtf((float)max(v, 1));
    cur[t] = excl;
    __syncthreads();
    for (int i = t; i < n; i += 256) {
        uint rc = recs[i];
        int p = atomicAdd(&cur[rc & 255u], 1);        // LDS atomic
        colst[p] = (int)(rc >> 8);
    }
    __syncthreads();
    for (int i = t; i < n; i += 256) col[s0 + i] = colst[i];
    if (b == 0) {
        if (t == 0) rp[NN] = NE;
        if (t < 64) col[NE + t] = 0;   // zero overshoot pad (safe gather target)
    }
}

// K6 merged: blocks [0,8192) = xs scale (float4->uint2); blocks [8192,8576) =
// all 6 layers' W transpose+bf16 convert (6*16384 = 98304 elems = 384 blocks).
__global__ __launch_bounds__(256) void k_scale_wconv(
        const float* __restrict__ hx, const float* __restrict__ ns,
        uint2* __restrict__ xs2,
        const float* __restrict__ W0, const float* __restrict__ W1,
        const float* __restrict__ W2, const float* __restrict__ W3,
        const float* __restrict__ W4, const float* __restrict__ W5,
        ushort* __restrict__ Wt) {
    if (blockIdx.x < 8192) {
        int i = blockIdx.x * 256 + threadIdx.x;   // over NN*32 float4 groups
        float4 v = ((const float4*)hx)[i];
        float s = ns[i >> 5];
        uint2 o;
        o.x = (uint)f2b(v.x * s) | ((uint)f2b(v.y * s) << 16);
        o.y = (uint)f2b(v.z * s) | ((uint)f2b(v.w * s) << 16);
        xs2[i] = o;
    } else {
        int t = (blockIdx.x - 8192) * 256 + threadIdx.x;  // 0..98303
        int l = t >> 14, r = t & 16383;
        const float* W = l == 0 ? W0 : l == 1 ? W1 : l == 2 ? W2
                       : l == 3 ? W3 : l == 4 ? W4 : W5;
        int n = r >> 7, k = r & 127;
        Wt[l * 16384 + n * 128 + k] = f2b(W[k * 128 + n]);
    }
}

// ---------------------------------------------------------------------------
// Fused conv layer — FROZEN from R8. At structural floor: NE*4 random 64B
// lines/dispatch, ~9.7 cy/line per-CU (L1 miss-queue ~64 / ~620cy L3 latency)
// = 33.1 us modeled vs ~33.5 measured. (R3 waves null, R4 sort null, R1/R5
// unroll spills, R8 scalar prefetch -1.5us, phasing rejected: XCD reuse ~1.)
// ---------------------------------------------------------------------------
#define ISSUE4(x0, x1, x2, x3, CR, K) { \
    int c0_ = __builtin_amdgcn_readlane((int)(CR), (K)); \
    int c1_ = __builtin_amdgcn_readlane((int)(CR), (K) + 1); \
    int c2_ = __builtin_amdgcn_readlane((int)(CR), (K) + 2); \
    int c3_ = __builtin_amdgcn_readlane((int)(CR), (K) + 3); \
    x0 = X32[(size_t)c0_ * 64 + lane]; \
    x1 = X32[(size_t)c1_ * 64 + lane]; \
    x2 = X32[(size_t)c2_ * 64 + lane]; \
    x3 = X32[(size_t)c3_ * 64 + lane]; }

#define FLUSHROWS(J) \
    while ((J) >= next_e && r < 15) { \
        *(float2*)&Af[r * 132 + 2 * lane] = make_float2(a0, a1); \
        a0 = 0.f; a1 = 0.f; r++; \
        next_e = __builtin_amdgcn_readlane(rpv, r + 1); }

#define PROC1(xv, J) { FLUSHROWS(J) \
    if ((J) < E) { a0 += bl(xv); a1 += bh(xv); } }

__global__ __launch_bounds__(64, 2) void k_fused(
        const uint* __restrict__ X32,     // xs as dwords: node*64 + lane
        const int* __restrict__ rp, const int* __restrict__ col,
        const float* __restrict__ nd, const float* __restrict__ ns,
        const uint4* __restrict__ Wg,     // Wt bf16 [n][k] as uint4: n*16+chunk
        const float* __restrict__ b, int do_scale,
        ushort* __restrict__ out) {
    __shared__ float Af[16 * 132];        // 8.25 KB; +4 dword row pad (banks)
    int lane = threadIdx.x;
    int rr = lane & 15;     // fragment row / C col
    int q = lane >> 4;      // fragment k-quad / C row-quad
    int nb = blockIdx.x * 16;

    // all row bounds in registers: rpv lane i holds rp[nb+i] (i<=16)
    int rpv = rp[nb + (lane < 16 ? lane : 16)];
    int S = __builtin_amdgcn_readlane(rpv, 0);
    int E = __builtin_amdgcn_readlane(rpv, 16);
    int r = 0;
    int next_e = __builtin_amdgcn_readlane(rpv, 1);
    float a0 = 0.f, a1 = 0.f;

    // col prefetch registers: lanes 0..15 hold 16 consecutive col values
    int c0 = col[S + rr];          // covers [S, S+16)
    int cA = col[S + 16 + rr];     // covers [S+16, S+32)

    uint xa0, xa1, xa2, xa3, xb0, xb1, xb2, xb3;
    uint xc0, xc1, xc2, xc3, xd0, xd1, xd2, xd3;
    int j = S;
    ISSUE4(xa0, xa1, xa2, xa3, c0, 0)
    ISSUE4(xb0, xb1, xb2, xb3, c0, 4)
    ISSUE4(xc0, xc1, xc2, xc3, c0, 8)
    ISSUE4(xd0, xd1, xd2, xd3, c0, 12)
    for (; j + 16 <= E; j += 16) {
        int cF = col[j + 32 + rr];          // prefetch next iter's cols
        PROC1(xa0, j)      PROC1(xa1, j + 1)  PROC1(xa2, j + 2)  PROC1(xa3, j + 3)
        ISSUE4(xa0, xa1, xa2, xa3, cA, 0)
        PROC1(xb0, j + 4)  PROC1(xb1, j + 5)  PROC1(xb2, j + 6)  PROC1(xb3, j + 7)
        ISSUE4(xb0, xb1, xb2, xb3, cA, 4)
        PROC1(xc0, j + 8)  PROC1(xc1, j + 9)  PROC1(xc2, j + 10) PROC1(xc3, j + 11)
        ISSUE4(xc0, xc1, xc2, xc3, cA, 8)
        PROC1(xd0, j + 12) PROC1(xd1, j + 13) PROC1(xd2, j + 14) PROC1(xd3, j + 15)
        ISSUE4(xd0, xd1, xd2, xd3, cA, 12)
        cA = cF;
    }
    PROC1(xa0, j)      PROC1(xa1, j + 1)  PROC1(xa2, j + 2)  PROC1(xa3, j + 3)
    PROC1(xb0, j + 4)  PROC1(xb1, j + 5)  PROC1(xb2, j + 6)  PROC1(xb3, j + 7)
    PROC1(xc0, j + 8)  PROC1(xc1, j + 9)  PROC1(xc2, j + 10) PROC1(xc3, j + 11)
    PROC1(xd0, j + 12) PROC1(xd1, j + 13) PROC1(xd2, j + 14) PROC1(xd3, j + 15)
    for (; r < 16; r++) {
        *(float2*)&Af[r * 132 + 2 * lane] = make_float2(a0, a1);
        a0 = 0.f; a1 = 0.f;
    }

    // A-fragments from LDS (scale by norm_dst), then MFMA
    float ndv = nd[nb + rr];
    bf16x8 afr[4];
    #pragma unroll
    for (int ks = 0; ks < 4; ks++) {
        const f32x4* Afv = (const f32x4*)&Af[rr * 132 + ks * 32 + q * 8];
        f32x4 v0 = Afv[0], v1 = Afv[1];
        union { u16x8 u; bf16x8 f; } cv;
        cv.u[0] = f2b(v0[0] * ndv); cv.u[1] = f2b(v0[1] * ndv);
        cv.u[2] = f2b(v0[2] * ndv); cv.u[3] = f2b(v0[3] * ndv);
        cv.u[4] = f2b(v1[0] * ndv); cv.u[5] = f2b(v1[1] * ndv);
        cv.u[6] = f2b(v1[2] * ndv); cv.u[7] = f2b(v1[3] * ndv);
        afr[ks] = cv.f;
    }

    f32x4 cacc[8] = {};
    #pragma unroll
    for (int ks = 0; ks < 4; ks++) {
        #pragma unroll
        for (int ni = 0; ni < 8; ni++) {
            union { uint4 u; bf16x8 f; } bw;
            bw.u = Wg[(size_t)(ni * 16 + rr) * 16 + ks * 4 + q];
            cacc[ni] = __builtin_amdgcn_mfma_f32_16x16x32_bf16(
                afr[ks], bw.f, cacc[ni], 0, 0, 0);
        }
    }

    // epilogue: bias + relu + (ns fold) -> bf16, staged in LDS (reuse Af)
    ushort* Cs = (ushort*)Af;             // [16][128]
    float sc4[4];
    #pragma unroll
    for (int rg = 0; rg < 4; rg++)
        sc4[rg] = do_scale ? ns[nb + q * 4 + rg] : 1.f;
    #pragma unroll
    for (int ni = 0; ni < 8; ni++) {
        int c = ni * 16 + rr;
        float bb = b[c];
        #pragma unroll
        for (int rg = 0; rg < 4; rg++) {
            float v = fmaxf(cacc[ni][rg] + bb, 0.f) * sc4[rg];
            Cs[(q * 4 + rg) * 128 + c] = f2b(v);
        }
    }
    const uint4* Cs4 = (const uint4*)Cs;
    uint4* Og = (uint4*)(out + (size_t)nb * 128);
    #pragma unroll
    for (int it = 0; it < 4; it++)
        Og[it * 64 + lane] = Cs4[it * 64 + lane];
}

// mean-pool + MLP head fused (R11): block per graph — inlined graph-range
// binary search, uint2 pooling reduce, then pred_lin MLP, no global roundtrip.
__global__ __launch_bounds__(256) void k_poolhead(
        const uint2* __restrict__ h2, const int* __restrict__ gid,
        const float* __restrict__ Wp1, const float* __restrict__ bp1,
        const float* __restrict__ Wp2, const float* __restrict__ bp2,
        float* __restrict__ scores) {
    __shared__ int se[2];
    __shared__ float4 part[256];
    __shared__ float p[128];
    __shared__ float t1[64];
    int g = blockIdx.x, t = threadIdx.x;
    if (t < 2) {
        int tgt = g + t;
        int lo = 0, hi = NN;
        while (lo < hi) { int mid = (lo + hi) >> 1; if (gid[mid] < tgt) lo = mid + 1; else hi = mid; }
        se[t] = lo;
    }
    __syncthreads();
    int s = se[0], e = se[1];
    int d2 = t & 31, qq = t >> 5;
    float4 acc = make_float4(0.f, 0.f, 0.f, 0.f);
    for (int i = s + qq; i < e; i += 8) {
        uint2 x = h2[(size_t)i * 32 + d2];
        acc.x += bl(x.x); acc.y += bh(x.x);
        acc.z += bl(x.y); acc.w += bh(x.y);
    }
    part[t] = acc;
    __syncthreads();
    if (t < 32) {
        float4 a = part[t];
        #pragma unroll
        for (int k = 1; k < 8; k++) {
            float4 pp = part[t + 32 * k];
            a.x += pp.x; a.y += pp.y; a.z += pp.z; a.w += pp.w;
        }
        float inv = 1.f / fmaxf((float)(e - s), 1.f);
        p[4 * t + 0] = a.x * inv; p[4 * t + 1] = a.y * inv;
        p[4 * t + 2] = a.z * inv; p[4 * t + 3] = a.w * inv;
    }
    __syncthreads();
    if (t < 64) {
        float a = 0.f;
        for (int k = 0; k < 128; k++) a += p[k] * Wp1[k * 64 + t];
        t1[t] = fmaxf(a + bp1[t], 0.f);
    }
    __syncthreads();
    if (t < NCLS) {
        float sacc = bp2[t];
        for (int k = 0; k < 64; k++) sacc += t1[k] * Wp2[k * NCLS + t];
        scores[g * NCLS + t] = sacc;
    }
}

extern "C" void kernel_launch(void* const* d_in, const int* in_sizes, int n_in,
                              void* d_out, int out_size, void* d_ws, size_t ws_size,
                              hipStream_t stream) {
    const float* hx  = (const float*)d_in[0];
    const int*   src = (const int*)d_in[1];
    const int*   dst = (const int*)d_in[2];
    const int*   gid = (const int*)d_in[3];
    const float* Ws[6], *bs[6];
    for (int l = 0; l < 6; l++) {
        Ws[l] = (const float*)d_in[5 + 2 * l];
        bs[l] = (const float*)d_in[6 + 2 * l];
    }
    const float* Wp1 = (const float*)d_in[17];
    const float* bp1 = (const float*)d_in[18];
    const float* Wp2 = (const float*)d_in[19];
    const float* bp2 = (const float*)d_in[20];
    float* scores = (float*)d_out;

    // ---- workspace layout (16B-aligned chunks) ----
    char* w = (char*)d_ws;
    ushort* xsA = (ushort*)w;     w += (size_t)NN * DF * 2;        // 16 MB
    ushort* xsB = (ushort*)w;     w += (size_t)NN * DF * 2;        // 16 MB
    ushort* Wt = (ushort*)w;      w += (size_t)6 * 128 * 128 * 2;  // 192 KB
    int* Md   = (int*)w;          w += 256 * 256 * 4;              // 256 KB
    int* Ms   = (int*)w;          w += 256 * 256 * 4;
    int* Bd   = (int*)w;          w += 256 * 256 * 4;
    int* Bs   = (int*)w;          w += 256 * 256 * 4;
    int* bbd  = (int*)w;          w += 257 * 4 + 12;
    int* bbs  = (int*)w;          w += 257 * 4 + 12;
    int* rp   = (int*)w;          w += (NN + 1) * 4 + 12;
    int* colv = (int*)w;          w += (NE + 64) * 4;              // +64 pad
    float* ns   = (float*)w;      w += NN * 4;
    float* ndst = (float*)w;      w += NN * 4;
    // bucket records alias the head of xsB (dead until k_fused layer 0,
    // which launches after k_bshist consumed them — stream-ordered)
    uint*   drec = (uint*)xsB;                          // 2 MB
    ushort* srec = (ushort*)((char*)xsB + (size_t)NE * 4);  // 1 MB

    k_hist<<<NBLK, 256, 0, stream>>>(src, dst, Md, Ms);
    k_colscan<<<2, 256, 0, stream>>>(Md, Ms, Bd, Bs, bbd, bbs);
    k_place<<<NBLK, 256, 0, stream>>>(src, dst, Bd, bbd, Bs, bbs, drec, srec);
    k_bshist<<<512, 256, 0, stream>>>(drec, bbd, srec, bbs, colv, rp, ndst, ns);
    k_scale_wconv<<<8192 + 384, 256, 0, stream>>>(
        hx, ns, (uint2*)xsA, Ws[0], Ws[1], Ws[2], Ws[3], Ws[4], Ws[5], Wt);

    ushort* cur = xsA;
    ushort* nxt = xsB;
    for (int l = 0; l < 6; l++) {
        k_fused<<<NN / 16, 64, 0, stream>>>(
            (const uint*)cur, rp, colv, ndst, ns,
            (const uint4*)(Wt + (size_t)l * 128 * 128), bs[l],
            (l < 5) ? 1 : 0, nxt);
        ushort* tmp = cur; cur = nxt; nxt = tmp;
    }

    k_poolhead<<<NG, 256, 0, stream>>>((const uint2*)cur, gid,
                                       Wp1, bp1, Wp2, bp2, scores);
}